// Round 1
// baseline (1338.351 us; speedup 1.0000x reference)
//
#include <hip/hip_runtime.h>
#include <math.h>

#define NB 4
#define NS 256
#define NV 200
#define NF 4
#define NG 80
#define NFG 320
#define NROT 16
#define F_TWO_PI 6.283185307179586f

// MODE 0: feat from input_feat; MODE 1: feat gathered from x_in, write x_out[B,S,4];
// MODE 2: gathered feat + final head -> d_out[B,S,1]
template<int MODE>
__global__ __launch_bounds__(NFG) void masif_block_kernel(
    const float* __restrict__ input_feat,
    const float* __restrict__ rho,
    const float* __restrict__ theta,
    const float* __restrict__ mask,
    const float* __restrict__ mu_rho,
    const float* __restrict__ mu_theta,
    const float* __restrict__ sigma_rho,
    const float* __restrict__ sigma_theta,
    const float* __restrict__ W_conv,
    const float* __restrict__ b_conv,
    const float* __restrict__ bn_gamma,
    const float* __restrict__ bn_beta,
    const float* __restrict__ bn_mean,
    const float* __restrict__ bn_var,
    const float* __restrict__ d1_w,
    const float* __restrict__ d1_b,
    const float* __restrict__ d2_w,
    const float* __restrict__ d2_b,
    const float* __restrict__ d3_w,
    const float* __restrict__ d3_b,
    const float* __restrict__ out_w,
    const float* __restrict__ out_b,
    const int*   __restrict__ indices,
    const float* __restrict__ x_in,
    float*       __restrict__ x_out)
{
    const int bs = blockIdx.x;            // 0..B*S-1
    const int t  = threadIdx.x;           // 0..319
    const int f  = t / NG;
    const int g  = t % NG;

    __shared__ float rho_s[NV];
    __shared__ float th_s[NV];
    __shared__ float thr_s[NV];
    __shared__ float msk_s[NV];
    __shared__ float feat_s[NV][NF];
    __shared__ float desc_s[NFG];
    __shared__ float x_s[NFG];
    __shared__ float y1_s[NG];
    __shared__ float y2_s[NF];
    __shared__ float y3_s[16];

    const int base = bs * NV;
    // stage per-vertex data
    for (int v = t; v < NV; v += NFG) {
        rho_s[v] = rho[base + v];
        th_s[v]  = theta[base + v];
        msk_s[v] = mask[base + v];
        float4 fv;
        if (MODE == 0) {
            fv = *reinterpret_cast<const float4*>(&input_feat[(size_t)(base + v) * NF]);
        } else {
            const int b   = bs / NS;
            const int idx = indices[base + v];
            fv = *reinterpret_cast<const float4*>(&x_in[(size_t)(b * NS + idx) * NF]);
        }
        feat_s[v][0] = fv.x; feat_s[v][1] = fv.y;
        feat_s[v][2] = fv.z; feat_s[v][3] = fv.w;
    }
    __syncthreads();

    // per-thread gaussian params for its (f,g) bin
    const float mu_r = mu_rho[t];
    const float mu_t = mu_theta[t];
    const float sr   = sigma_rho[t];
    const float st   = sigma_theta[t];
    const float isr  = 1.0f / (sr * sr + 1e-5f);
    const float ist  = 1.0f / (st * st + 1e-5f);

    float cmax = -INFINITY;

    for (int r = 0; r < NROT; ++r) {
        const float off = (float)r * (F_TWO_PI / (float)NROT);
        for (int v = t; v < NV; v += NFG)
            thr_s[v] = fmodf(th_s[v] + off, F_TWO_PI);
        __syncthreads();

        float num = 0.0f, den = 0.0f;
        #pragma unroll 4
        for (int v = 0; v < NV; ++v) {
            const float dr = rho_s[v] - mu_r;
            const float dt = thr_s[v] - mu_t;
            const float e  = __expf(-(dr * dr * isr + dt * dt * ist)) * msk_s[v];
            den += e;
            num += e * feat_s[v][f];
        }
        desc_s[t] = num / (den + 1e-5f);
        __syncthreads();

        // conv: thread t computes conv[f][h] with h = g
        float c = b_conv[t];
        const float* Wp = &W_conv[(size_t)f * NG * NG + g];
        const float* dp = &desc_s[f * NG];
        #pragma unroll 8
        for (int gg = 0; gg < NG; ++gg)
            c += dp[gg] * Wp[(size_t)gg * NG];
        cmax = fmaxf(cmax, c);
        __syncthreads();   // before thr_s/desc_s are overwritten next rotation
    }

    // batchnorm + relu, x index == t (f*G + h layout matches reshape)
    {
        const float xv = (cmax - bn_mean[t]) * rsqrtf(bn_var[t] + 1e-3f) * bn_gamma[t] + bn_beta[t];
        x_s[t] = fmaxf(xv, 0.0f);
    }
    __syncthreads();

    // d1: 320 -> 80, relu
    if (t < NG) {
        float a = d1_b[t];
        #pragma unroll 8
        for (int i = 0; i < NFG; ++i)
            a += x_s[i] * d1_w[(size_t)i * NG + t];
        y1_s[t] = fmaxf(a, 0.0f);
    }
    __syncthreads();

    // d2: 80 -> 4, relu
    if (t < NF) {
        float a = d2_b[t];
        #pragma unroll 8
        for (int i = 0; i < NG; ++i)
            a += y1_s[i] * d2_w[(size_t)i * NF + t];
        a = fmaxf(a, 0.0f);
        if (MODE < 2) {
            x_out[(size_t)bs * NF + t] = a;
        } else {
            y2_s[t] = a;
        }
    }

    if (MODE == 2) {
        __syncthreads();
        // d3: 4 -> 16, relu
        if (t < 16) {
            float a = d3_b[t];
            #pragma unroll
            for (int ff = 0; ff < NF; ++ff)
                a += y2_s[ff] * d3_w[ff * 16 + t];
            y3_s[t] = fmaxf(a, 0.0f);
        }
        __syncthreads();
        if (t == 0) {
            float a = out_b[0];
            #pragma unroll
            for (int j = 0; j < 16; ++j)
                a += y3_s[j] * out_w[j];
            x_out[bs] = a;
        }
    }
}

extern "C" void kernel_launch(void* const* d_in, const int* in_sizes, int n_in,
                              void* d_out, int out_size, void* d_ws, size_t ws_size,
                              hipStream_t stream) {
    const float* input_feat  = (const float*)d_in[0];
    const float* rho         = (const float*)d_in[1];
    const float* theta       = (const float*)d_in[2];
    const float* mask        = (const float*)d_in[3];
    const float* mu_rho      = (const float*)d_in[4];
    const float* mu_theta    = (const float*)d_in[5];
    const float* sigma_rho   = (const float*)d_in[6];
    const float* sigma_theta = (const float*)d_in[7];
    const float* W_conv      = (const float*)d_in[8];
    const float* b_conv      = (const float*)d_in[9];
    const float* bn_gamma    = (const float*)d_in[10];
    const float* bn_beta     = (const float*)d_in[11];
    const float* bn_mean     = (const float*)d_in[12];
    const float* bn_var      = (const float*)d_in[13];
    const float* d1_w        = (const float*)d_in[14];
    const float* d1_b        = (const float*)d_in[15];
    const float* d2_w        = (const float*)d_in[16];
    const float* d2_b        = (const float*)d_in[17];
    const float* d3_w        = (const float*)d_in[18];
    const float* d3_b        = (const float*)d_in[19];
    const float* out_w       = (const float*)d_in[20];
    const float* out_b       = (const float*)d_in[21];
    const int*   indices     = (const int*)d_in[22];

    float* x1 = (float*)d_ws;                  // [B*S*4]
    float* x2 = x1 + (size_t)NB * NS * NF;     // [B*S*4]
    float* out = (float*)d_out;                // [B*S]

    dim3 grid(NB * NS), block(NFG);

    masif_block_kernel<0><<<grid, block, 0, stream>>>(
        input_feat, rho, theta, mask, mu_rho, mu_theta, sigma_rho, sigma_theta,
        W_conv, b_conv, bn_gamma, bn_beta, bn_mean, bn_var,
        d1_w, d1_b, d2_w, d2_b, d3_w, d3_b, out_w, out_b,
        indices, nullptr, x1);

    masif_block_kernel<1><<<grid, block, 0, stream>>>(
        input_feat, rho, theta, mask, mu_rho, mu_theta, sigma_rho, sigma_theta,
        W_conv, b_conv, bn_gamma, bn_beta, bn_mean, bn_var,
        d1_w, d1_b, d2_w, d2_b, d3_w, d3_b, out_w, out_b,
        indices, x1, x2);

    masif_block_kernel<2><<<grid, block, 0, stream>>>(
        input_feat, rho, theta, mask, mu_rho, mu_theta, sigma_rho, sigma_theta,
        W_conv, b_conv, bn_gamma, bn_beta, bn_mean, bn_var,
        d1_w, d1_b, d2_w, d2_b, d3_w, d3_b, out_w, out_b,
        indices, x2, out);
}

// Round 2
// 470.210 us; speedup vs baseline: 2.8463x; 2.8463x over previous
//
#include <hip/hip_runtime.h>
#include <math.h>

#define NB 4
#define NS 256
#define NV 200
#define NF 4
#define NG 80
#define NFG 320
#define NROT 16
#define TWO_PI_F 6.28318530717958647692f
#define DELTA_F 0.39269908169872414f

typedef __attribute__((ext_vector_type(8))) short short8v;   // 8 bf16 (4 VGPRs)
typedef __attribute__((ext_vector_type(4))) float floatx4;   // MFMA acc

// Tang region: [256 j][40 u16] hi + lo (20480B each); reused as D_s [256][26] f32
// Afe  region: [32 i][240 u16] hi + lo (15360B each); reused as desc_s [4][80][16] f32
#define TANG_ROW 40
#define AFE_ROW 240
#define D_ROW 26

template<int MODE>
__global__ __launch_bounds__(NFG, 2) void masif_block_kernel(
    const float* __restrict__ input_feat,
    const float* __restrict__ rho,
    const float* __restrict__ theta,
    const float* __restrict__ mask,
    const float* __restrict__ mu_rho,
    const float* __restrict__ mu_theta,
    const float* __restrict__ sigma_rho,
    const float* __restrict__ sigma_theta,
    const float* __restrict__ W_conv,
    const float* __restrict__ b_conv,
    const float* __restrict__ bn_gamma,
    const float* __restrict__ bn_beta,
    const float* __restrict__ bn_mean,
    const float* __restrict__ bn_var,
    const float* __restrict__ d1_w,
    const float* __restrict__ d1_b,
    const float* __restrict__ d2_w,
    const float* __restrict__ d2_b,
    const float* __restrict__ d3_w,
    const float* __restrict__ d3_b,
    const float* __restrict__ out_w,
    const float* __restrict__ out_b,
    const int*   __restrict__ indices,
    const float* __restrict__ x_in,
    float*       __restrict__ x_out)
{
    const int bs = blockIdx.x;          // patch id
    const int t  = threadIdx.x;         // 0..319

    __shared__ __align__(16) char sm0[2 * 256 * TANG_ROW * 2];   // 40960B
    __shared__ __align__(16) char sm1[2 * 32 * AFE_ROW * 2];     // 30720B
    __shared__ float theta_s[224];
    __shared__ float mu_r_s[5];
    __shared__ float mu_t_s[16];
    __shared__ float off_s[16];
    __shared__ float x_s[NFG];
    __shared__ float y1_s[NG];
    __shared__ float y2_s[NF];
    __shared__ float y3_s[16];

    unsigned short* tang_h = (unsigned short*)sm0;                    // [256][40]
    unsigned short* tang_l = (unsigned short*)(sm0 + 256 * TANG_ROW * 2);
    float*          D_s    = (float*)sm0;                             // [256][26]
    unsigned short* afe_h  = (unsigned short*)sm1;                    // [32][240]
    unsigned short* afe_l  = (unsigned short*)(sm1 + 32 * AFE_ROW * 2);
    float*          desc_s = (float*)sm1;                             // [4][80][16]

    const int base = bs * NV;
    const int b    = bs / NS;

    // ---- scalars ----
    const float sr  = sigma_rho[0];
    const float st  = sigma_theta[0];
    const float isr = 1.0f / (sr * sr + 1e-5f);
    const float ist = 1.0f / (st * st + 1e-5f);

    // ---- small tables ----
    if (t < 16) { mu_t_s[t] = mu_theta[t]; off_s[t] = (float)t * DELTA_F; }
    if (t < 5)  { mu_r_s[t] = mu_rho[t * 16]; }
    for (int v = t; v < 224; v += NFG)
        theta_s[v] = (v < NV) ? theta[base + v] : 0.0f;
    __syncthreads();

    // ---- build Afe[i=(f'*5+ri)][v] in split-bf16 ----
    if (t < 224) {
        const int v = t;
        float rv = 0.0f, mv = 0.0f;
        float4 fv = {0.0f, 0.0f, 0.0f, 0.0f};
        if (v < NV) {
            rv = rho[base + v];
            mv = mask[base + v];
            if (MODE == 0) {
                fv = *reinterpret_cast<const float4*>(&input_feat[(size_t)(base + v) * NF]);
            } else {
                const int idx = indices[base + v];
                fv = *reinterpret_cast<const float4*>(&x_in[(size_t)(b * NS + idx) * NF]);
            }
        }
        float w[5] = {mv, mv * fv.x, mv * fv.y, mv * fv.z, mv * fv.w};
        #pragma unroll
        for (int ri = 0; ri < 5; ++ri) {
            const float dr = rv - mu_r_s[ri];
            const float R  = __expf(dr * dr * (-isr));
            #pragma unroll
            for (int fp = 0; fp < 5; ++fp) {
                const float e = w[fp] * R;
                const unsigned u  = __float_as_uint(e);
                const unsigned hi = u & 0xffff0000u;
                const float    lo = e - __uint_as_float(hi);
                const int i = fp * 5 + ri;
                afe_h[i * AFE_ROW + v] = (unsigned short)(u >> 16);
                afe_l[i * AFE_ROW + v] = (unsigned short)(__float_as_uint(lo) >> 16);
            }
        }
    } else {
        // zero rows 25..31 of both afe arrays (read as B-frag pad)
        for (int z = t - 224; z < 7 * AFE_ROW; z += 96) {
            afe_h[25 * AFE_ROW + z] = 0;
            afe_l[25 * AFE_ROW + z] = 0;
        }
    }

    // ---- K-loop: 7 steps of 32 vertices; Tang build then MFMA ----
    const int wv   = t >> 6;       // wave 0..4
    const int lane = t & 63;
    const int lr   = lane & 15;
    const int lk   = lane >> 4;

    floatx4 acc[7];
    #pragma unroll
    for (int ci = 0; ci < 7; ++ci) acc[ci] = floatx4{0.f, 0.f, 0.f, 0.f};

    const int vloc = t & 31;
    const int j0   = t >> 5;       // 0..9

    for (int kb = 0; kb < 7; ++kb) {
        // build TangT[j][vloc] split-bf16 for this vertex block
        const float th = theta_s[kb * 32 + vloc];
        for (int j = j0; j < 256; j += 10) {
            const int r  = j >> 4;
            const int ti = j & 15;
            float s = th + off_s[r];
            s -= (s >= TWO_PI_F) ? TWO_PI_F : 0.0f;
            const float dt = s - mu_t_s[ti];
            const float e  = __expf(dt * dt * (-ist));
            const unsigned u  = __float_as_uint(e);
            const unsigned hi = u & 0xffff0000u;
            const float    lo = e - __uint_as_float(hi);
            tang_h[j * TANG_ROW + vloc] = (unsigned short)(u >> 16);
            tang_l[j * TANG_ROW + vloc] = (unsigned short)(__float_as_uint(lo) >> 16);
        }
        __syncthreads();

        // MFMA: C[j, i] += Tang[j, k] * Afe[i, k]
        #pragma unroll
        for (int ci = 0; ci < 7; ++ci) {
            const int tile = wv + 5 * ci;
            if (tile < 32) {
                const int mt = tile >> 1;
                const int nt = tile & 1;
                const short8v ah = *(const short8v*)&tang_h[(16 * mt + lr) * TANG_ROW + 8 * lk];
                const short8v al = *(const short8v*)&tang_l[(16 * mt + lr) * TANG_ROW + 8 * lk];
                const short8v bh = *(const short8v*)&afe_h[(16 * nt + lr) * AFE_ROW + kb * 32 + 8 * lk];
                const short8v bl = *(const short8v*)&afe_l[(16 * nt + lr) * AFE_ROW + kb * 32 + 8 * lk];
                acc[ci] = __builtin_amdgcn_mfma_f32_16x16x32_bf16(ah, bh, acc[ci], 0, 0, 0);
                acc[ci] = __builtin_amdgcn_mfma_f32_16x16x32_bf16(ah, bl, acc[ci], 0, 0, 0);
                acc[ci] = __builtin_amdgcn_mfma_f32_16x16x32_bf16(al, bh, acc[ci], 0, 0, 0);
            }
        }
        __syncthreads();
    }

    // ---- write D[j][i] (overlaps Tang region) ----
    #pragma unroll
    for (int ci = 0; ci < 7; ++ci) {
        const int tile = wv + 5 * ci;
        if (tile < 32) {
            const int mt = tile >> 1;
            const int nt = tile & 1;
            const int i  = 16 * nt + lr;
            if (i < 25) {
                #pragma unroll
                for (int q = 0; q < 4; ++q) {
                    const int jrow = 16 * mt + 4 * lk + q;
                    D_s[jrow * D_ROW + i] = acc[ci][q];
                }
            }
        }
    }
    __syncthreads();

    // ---- desc[f][g][r] = num/(den+eps) (overlaps Afe region) ----
    for (int e = t; e < NF * NG * NROT; e += NFG) {
        const int f   = e / (NG * NROT);
        const int rem = e - f * (NG * NROT);
        const int g   = rem >> 4;
        const int r   = rem & 15;
        const int ri  = g >> 4;
        const int ti  = g & 15;
        const int j   = r * 16 + ti;
        const float num = D_s[j * D_ROW + (f + 1) * 5 + ri];
        const float den = D_s[j * D_ROW + ri];
        desc_s[e] = __fdividef(num, den + 1e-5f);
    }
    __syncthreads();

    // ---- conv (all rotations together, W reused 16x) + rot-max + BN + relu ----
    {
        const int f = t / NG;
        const int h = t - f * NG;
        float a0 = 0.f, a1 = 0.f, a2 = 0.f, a3 = 0.f, a4 = 0.f, a5 = 0.f, a6 = 0.f, a7 = 0.f;
        float a8 = 0.f, a9 = 0.f, a10 = 0.f, a11 = 0.f, a12 = 0.f, a13 = 0.f, a14 = 0.f, a15 = 0.f;
        const float* Wp = W_conv + (size_t)f * NG * NG + h;
        const float* dp = desc_s + f * (NG * NROT);
        #pragma unroll 2
        for (int gg = 0; gg < NG; ++gg) {
            const float wval = Wp[(size_t)gg * NG];
            const float4* dd = reinterpret_cast<const float4*>(dp + (gg << 4));
            const float4 q0 = dd[0], q1 = dd[1], q2 = dd[2], q3 = dd[3];
            a0  = fmaf(q0.x, wval, a0);  a1  = fmaf(q0.y, wval, a1);
            a2  = fmaf(q0.z, wval, a2);  a3  = fmaf(q0.w, wval, a3);
            a4  = fmaf(q1.x, wval, a4);  a5  = fmaf(q1.y, wval, a5);
            a6  = fmaf(q1.z, wval, a6);  a7  = fmaf(q1.w, wval, a7);
            a8  = fmaf(q2.x, wval, a8);  a9  = fmaf(q2.y, wval, a9);
            a10 = fmaf(q2.z, wval, a10); a11 = fmaf(q2.w, wval, a11);
            a12 = fmaf(q3.x, wval, a12); a13 = fmaf(q3.y, wval, a13);
            a14 = fmaf(q3.z, wval, a14); a15 = fmaf(q3.w, wval, a15);
        }
        float m0 = fmaxf(fmaxf(fmaxf(a0, a1), fmaxf(a2, a3)), fmaxf(fmaxf(a4, a5), fmaxf(a6, a7)));
        float m1 = fmaxf(fmaxf(fmaxf(a8, a9), fmaxf(a10, a11)), fmaxf(fmaxf(a12, a13), fmaxf(a14, a15)));
        const float cm = fmaxf(m0, m1) + b_conv[t];
        const float xv = (cm - bn_mean[t]) * rsqrtf(bn_var[t] + 1e-3f) * bn_gamma[t] + bn_beta[t];
        x_s[t] = fmaxf(xv, 0.0f);
    }
    __syncthreads();

    // ---- d1: 320 -> 80, relu ----
    if (t < NG) {
        float a = d1_b[t];
        #pragma unroll 8
        for (int i = 0; i < NFG; ++i)
            a = fmaf(x_s[i], d1_w[(size_t)i * NG + t], a);
        y1_s[t] = fmaxf(a, 0.0f);
    }
    __syncthreads();

    // ---- d2: 80 -> 4, relu ----
    if (t < NF) {
        float a = d2_b[t];
        #pragma unroll 8
        for (int i = 0; i < NG; ++i)
            a = fmaf(y1_s[i], d2_w[(size_t)i * NF + t], a);
        a = fmaxf(a, 0.0f);
        if (MODE < 2) x_out[(size_t)bs * NF + t] = a;
        else          y2_s[t] = a;
    }

    if (MODE == 2) {
        __syncthreads();
        if (t < 16) {
            float a = d3_b[t];
            #pragma unroll
            for (int ff = 0; ff < NF; ++ff)
                a = fmaf(y2_s[ff], d3_w[ff * 16 + t], a);
            y3_s[t] = fmaxf(a, 0.0f);
        }
        __syncthreads();
        if (t == 0) {
            float a = out_b[0];
            #pragma unroll
            for (int k = 0; k < 16; ++k)
                a = fmaf(y3_s[k], out_w[k], a);
            x_out[bs] = a;
        }
    }
}

extern "C" void kernel_launch(void* const* d_in, const int* in_sizes, int n_in,
                              void* d_out, int out_size, void* d_ws, size_t ws_size,
                              hipStream_t stream) {
    const float* input_feat  = (const float*)d_in[0];
    const float* rho         = (const float*)d_in[1];
    const float* theta       = (const float*)d_in[2];
    const float* mask        = (const float*)d_in[3];
    const float* mu_rho      = (const float*)d_in[4];
    const float* mu_theta    = (const float*)d_in[5];
    const float* sigma_rho   = (const float*)d_in[6];
    const float* sigma_theta = (const float*)d_in[7];
    const float* W_conv      = (const float*)d_in[8];
    const float* b_conv      = (const float*)d_in[9];
    const float* bn_gamma    = (const float*)d_in[10];
    const float* bn_beta     = (const float*)d_in[11];
    const float* bn_mean     = (const float*)d_in[12];
    const float* bn_var      = (const float*)d_in[13];
    const float* d1_w        = (const float*)d_in[14];
    const float* d1_b        = (const float*)d_in[15];
    const float* d2_w        = (const float*)d_in[16];
    const float* d2_b        = (const float*)d_in[17];
    const float* d3_w        = (const float*)d_in[18];
    const float* d3_b        = (const float*)d_in[19];
    const float* out_w       = (const float*)d_in[20];
    const float* out_b       = (const float*)d_in[21];
    const int*   indices     = (const int*)d_in[22];

    float* x1  = (float*)d_ws;
    float* x2  = x1 + (size_t)NB * NS * NF;
    float* out = (float*)d_out;

    dim3 grid(NB * NS), block(NFG);

    masif_block_kernel<0><<<grid, block, 0, stream>>>(
        input_feat, rho, theta, mask, mu_rho, mu_theta, sigma_rho, sigma_theta,
        W_conv, b_conv, bn_gamma, bn_beta, bn_mean, bn_var,
        d1_w, d1_b, d2_w, d2_b, d3_w, d3_b, out_w, out_b, indices, nullptr, x1);

    masif_block_kernel<1><<<grid, block, 0, stream>>>(
        input_feat, rho, theta, mask, mu_rho, mu_theta, sigma_rho, sigma_theta,
        W_conv, b_conv, bn_gamma, bn_beta, bn_mean, bn_var,
        d1_w, d1_b, d2_w, d2_b, d3_w, d3_b, out_w, out_b, indices, x1, x2);

    masif_block_kernel<2><<<grid, block, 0, stream>>>(
        input_feat, rho, theta, mask, mu_rho, mu_theta, sigma_rho, sigma_theta,
        W_conv, b_conv, bn_gamma, bn_beta, bn_mean, bn_var,
        d1_w, d1_b, d2_w, d2_b, d3_w, d3_b, out_w, out_b, indices, x2, out);
}

// Round 4
// 276.956 us; speedup vs baseline: 4.8324x; 1.6978x over previous
//
#include <hip/hip_runtime.h>
#include <math.h>

#define NB 4
#define NS 256
#define NV 200
#define NVP 224
#define NF 4
#define NG 80
#define NFG 320
#define NROT 16
#define TWO_PI_F 6.28318530717958647692f
#define DELTA_F 0.39269908169872414f      // 2pi/16
#define INV_DELTA_F 2.5464790894703254f   // 16/2pi

#define AFE_ROW 248     // u16 (496B row: 2-way banks, 16B aligned)
#define T_ROW 31        // u32
#define D_ROW 26        // f32
#define DESC_ROW 104    // u16 (208B row)

// region1 must hold BOTH overlays:
//   afe:  2 * 26 * AFE_ROW * 2  = 25792 B
//   desc: 2 * 64 * DESC_ROW * 2 = 26624 B   <-- max (R3 bug: was sized to afe only)
#define REG1_BYTES (2 * 64 * DESC_ROW * 2)

typedef __attribute__((ext_vector_type(8))) short short8v;   // 8 bf16
typedef __attribute__((ext_vector_type(4))) float floatx4;   // MFMA acc
typedef __attribute__((ext_vector_type(4))) unsigned int uintx4;

__device__ __forceinline__ short8v mk_frag(unsigned a, unsigned b, unsigned c, unsigned d) {
    uintx4 v = {a, b, c, d};
    return __builtin_bit_cast(short8v, v);
}

template<int MODE>
__global__ __launch_bounds__(NFG, 2) void masif_block_kernel(
    const float* __restrict__ input_feat,
    const float* __restrict__ rho,
    const float* __restrict__ theta,
    const float* __restrict__ mask,
    const float* __restrict__ mu_rho,
    const float* __restrict__ sigma_rho,
    const float* __restrict__ sigma_theta,
    const float* __restrict__ W_conv,
    const float* __restrict__ b_conv,
    const float* __restrict__ bn_gamma,
    const float* __restrict__ bn_beta,
    const float* __restrict__ bn_mean,
    const float* __restrict__ bn_var,
    const float* __restrict__ d1_w,
    const float* __restrict__ d1_b,
    const float* __restrict__ d2_w,
    const float* __restrict__ d2_b,
    const float* __restrict__ d3_w,
    const float* __restrict__ d3_b,
    const float* __restrict__ out_w,
    const float* __restrict__ out_b,
    const int*   __restrict__ indices,
    const float* __restrict__ x_in,
    float*       __restrict__ x_out)
{
    const int bs = blockIdx.x;
    const int t  = threadIdx.x;
    const int lane = t & 63;
    const int lr   = lane & 15;
    const int lk   = lane >> 4;
    const int wv   = t >> 6;          // wave 0..4

    // region0: T table (u32 packed hi/lo bf16) [224][31] = 27776B; overlay D_s f32 [256][26] = 26624B
    __shared__ __align__(16) char reg0[NVP * T_ROW * 4];
    // region1: afe_h|afe_l u16 [26][248] each; overlay desc_h|desc_l u16 [64][104] each
    __shared__ __align__(16) char reg1[REG1_BYTES];
    __shared__ unsigned int q_s[NVP];
    __shared__ float th_s[NVP];
    __shared__ float x_s[NFG];
    __shared__ float y1p[4 * NG];
    __shared__ float y1_s[NG];
    __shared__ float y2_s[NF];
    __shared__ float y3_s[16];

    unsigned int*   T32    = (unsigned int*)reg0;
    float*          D_s    = (float*)reg0;
    unsigned short* afe_h  = (unsigned short*)reg1;
    unsigned short* afe_l  = afe_h + 26 * AFE_ROW;
    unsigned short* desc_h = (unsigned short*)reg1;
    unsigned short* desc_l = desc_h + 4 * 16 * DESC_ROW;

    const int base = bs * NV;
    const int b    = bs / NS;

    const float sr  = sigma_rho[0];
    const float st  = sigma_theta[0];
    const float isr = 1.0f / (sr * sr + 1e-5f);
    const float ist = 1.0f / (st * st + 1e-5f);

    // ---- phase A: stage theta, build Afe rows (i = fp*5+ri), zero row 25 ----
    if (t < NVP) {
        const int v = t;
        float rv = 0.0f, mv = 0.0f, thv = 0.0f;
        float4 fv = {0.f, 0.f, 0.f, 0.f};
        if (v < NV) {
            rv  = rho[base + v];
            mv  = mask[base + v];
            thv = theta[base + v];
            if (MODE == 0) {
                fv = *reinterpret_cast<const float4*>(&input_feat[(size_t)(base + v) * NF]);
            } else {
                const int idx = indices[base + v];
                fv = *reinterpret_cast<const float4*>(&x_in[(size_t)(b * NS + idx) * NF]);
            }
        }
        th_s[v] = thv;
        const float w5[5] = {mv, mv * fv.x, mv * fv.y, mv * fv.z, mv * fv.w};
        #pragma unroll
        for (int ri = 0; ri < 5; ++ri) {
            const float dr = rv - mu_rho[ri * 16];
            const float R  = __expf(-(dr * dr) * isr);
            #pragma unroll
            for (int fp = 0; fp < 5; ++fp) {
                const float val = w5[fp] * R;
                const unsigned u  = __float_as_uint(val);
                const unsigned hb = u & 0xffff0000u;
                const float    lo = val - __uint_as_float(hb);
                const int i = fp * 5 + ri;
                afe_h[i * AFE_ROW + v] = (unsigned short)(u >> 16);
                afe_l[i * AFE_ROW + v] = (unsigned short)(__float_as_uint(lo) >> 16);
            }
        }
    } else {
        for (int z = t - NVP; z < AFE_ROW; z += NFG - NVP) {
            afe_h[25 * AFE_ROW + z] = 0;
            afe_l[25 * AFE_ROW + z] = 0;
        }
    }
    __syncthreads();

    // ---- phase B: T table: T[v][d] = exp(-(a + (d-15)*DELTA)^2 * ist), packed hi/lo bf16 ----
    for (int e = t; e < NVP * T_ROW; e += NFG) {
        const int v = e / T_ROW;
        const int d = e - v * T_ROW;
        const float th = th_s[v];
        const float qf = floorf(th * INV_DELTA_F);
        const float a  = fmaf(-qf, DELTA_F, th);
        const float dt = fmaf((float)(d - 15), DELTA_F, a);
        const float val = __expf(-(dt * dt) * ist);
        const unsigned u  = __float_as_uint(val);
        const unsigned hb = u & 0xffff0000u;
        const float    lo = val - __uint_as_float(hb);
        T32[e] = hb | (__float_as_uint(lo) >> 16);
        if (d == 0) q_s[v] = ((unsigned)(int)qf) & 15u;
    }
    __syncthreads();

    // ---- stage 1: D[j=(r,ti)][i] = sum_v Tang[j,v]*Afe[i,v]; barrier-free K-loop ----
    floatx4 acc[7];
    #pragma unroll
    for (int ci = 0; ci < 7; ++ci) acc[ci] = floatx4{0.f, 0.f, 0.f, 0.f};

    const int i1c = (16 + lr) <= 24 ? (16 + lr) : 25;   // clamped B row for nt=1

    for (int kb = 0; kb < 7; ++kb) {
        const int vb = kb * 32 + 8 * lk;
        unsigned q8[8]; int tb[8];
        #pragma unroll
        for (int e = 0; e < 8; ++e) { q8[e] = q_s[vb + e]; tb[e] = (vb + e) * T_ROW + 15 - lr; }
        const int co = vb;   // column offset in afe rows
        const short8v bh0 = *(const short8v*)&afe_h[lr * AFE_ROW + co];
        const short8v bl0 = *(const short8v*)&afe_l[lr * AFE_ROW + co];
        const short8v bh1 = *(const short8v*)&afe_h[i1c * AFE_ROW + co];
        const short8v bl1 = *(const short8v*)&afe_l[i1c * AFE_ROW + co];

        #pragma unroll
        for (int ci = 0; ci < 7; ++ci) {
            const int tile = wv + 5 * ci;
            if (tile < 32) {
                const int mt = tile >> 1;   // rotation r (A rows j=16*mt+lr -> r=mt, ti=lr)
                unsigned hp[4], lp[4];
                #pragma unroll
                for (int w2 = 0; w2 < 4; ++w2) {
                    const int e0 = 2 * w2, e1 = 2 * w2 + 1;
                    const unsigned u0 = T32[tb[e0] + (int)((q8[e0] + mt) & 15u)];
                    const unsigned u1 = T32[tb[e1] + (int)((q8[e1] + mt) & 15u)];
                    hp[w2] = (u0 >> 16) | (u1 & 0xffff0000u);
                    lp[w2] = (u0 & 0xffffu) | (u1 << 16);
                }
                const short8v ah = mk_frag(hp[0], hp[1], hp[2], hp[3]);
                const short8v al = mk_frag(lp[0], lp[1], lp[2], lp[3]);
                const short8v bh = (tile & 1) ? bh1 : bh0;
                const short8v bl = (tile & 1) ? bl1 : bl0;
                acc[ci] = __builtin_amdgcn_mfma_f32_16x16x32_bf16(ah, bh, acc[ci], 0, 0, 0);
                acc[ci] = __builtin_amdgcn_mfma_f32_16x16x32_bf16(ah, bl, acc[ci], 0, 0, 0);
                acc[ci] = __builtin_amdgcn_mfma_f32_16x16x32_bf16(al, bh, acc[ci], 0, 0, 0);
            }
        }
    }
    __syncthreads();   // done reading T32/afe

    // ---- write D_s [256][26] over T region ----
    #pragma unroll
    for (int ci = 0; ci < 7; ++ci) {
        const int tile = wv + 5 * ci;
        if (tile < 32) {
            const int mt = tile >> 1;
            const int nt = tile & 1;
            const int i  = 16 * nt + lr;
            if (i < 25) {
                #pragma unroll
                for (int q = 0; q < 4; ++q)
                    D_s[(16 * mt + 4 * lk + q) * D_ROW + i] = acc[ci][q];
            }
        }
    }
    __syncthreads();

    // ---- desc[f][r][g] = num/(den+eps), split-bf16, g padded to 96 (rows 104) ----
    for (int e = t; e < 4 * 16 * 96; e += NFG) {
        const int f   = e / 1536;
        const int rem = e - f * 1536;
        const int r   = rem / 96;
        const int g   = rem - r * 96;
        float dv = 0.0f;
        if (g < NG) {
            const int ti = g & 15, ri = g >> 4;
            const int j  = r * 16 + ti;
            const float den = D_s[j * D_ROW + ri];
            const float num = D_s[j * D_ROW + (f + 1) * 5 + ri];
            dv = __fdividef(num, den + 1e-5f);
        }
        const unsigned u  = __float_as_uint(dv);
        const unsigned hb = u & 0xffff0000u;
        const float    lo = dv - __uint_as_float(hb);
        desc_h[(f * 16 + r) * DESC_ROW + g] = (unsigned short)(u >> 16);
        desc_l[(f * 16 + r) * DESC_ROW + g] = (unsigned short)(__float_as_uint(lo) >> 16);
    }
    __syncthreads();

    // ---- stage 3: conv as MFMA. C[r][h] = sum_g desc[f][r][g] * W[f][g][h]; wave wv owns h-tile nt=wv ----
    {
        const int hcol = 16 * wv + lr;   // 0..79
        floatx4 acc2[4];
        #pragma unroll
        for (int f = 0; f < 4; ++f) acc2[f] = floatx4{0.f, 0.f, 0.f, 0.f};

        #pragma unroll
        for (int f = 0; f < 4; ++f) {
            #pragma unroll
            for (int ks = 0; ks < 3; ++ks) {
                const int g0 = ks * 32 + 8 * lk;
                unsigned wh[4], wl[4];
                #pragma unroll
                for (int w2 = 0; w2 < 4; ++w2) {
                    const int ga = g0 + 2 * w2, gb = ga + 1;
                    float v0 = 0.f, v1 = 0.f;
                    if (ga < NG) v0 = W_conv[((size_t)(f * NG + ga)) * NG + hcol];
                    if (gb < NG) v1 = W_conv[((size_t)(f * NG + gb)) * NG + hcol];
                    const unsigned ua = __float_as_uint(v0);
                    const unsigned ha = ua & 0xffff0000u;
                    const float    la = v0 - __uint_as_float(ha);
                    const unsigned ub = __float_as_uint(v1);
                    const unsigned hb2 = ub & 0xffff0000u;
                    const float    lb = v1 - __uint_as_float(hb2);
                    wh[w2] = (ua >> 16) | hb2;
                    wl[w2] = (__float_as_uint(la) >> 16) | (__float_as_uint(lb) & 0xffff0000u);
                }
                const short8v wfh = mk_frag(wh[0], wh[1], wh[2], wh[3]);
                const short8v wfl = mk_frag(wl[0], wl[1], wl[2], wl[3]);
                const int db = (f * 16 + lr) * DESC_ROW + g0;
                const short8v dh = *(const short8v*)&desc_h[db];
                const short8v dl = *(const short8v*)&desc_l[db];
                acc2[f] = __builtin_amdgcn_mfma_f32_16x16x32_bf16(dh, wfh, acc2[f], 0, 0, 0);
                acc2[f] = __builtin_amdgcn_mfma_f32_16x16x32_bf16(dh, wfl, acc2[f], 0, 0, 0);
                acc2[f] = __builtin_amdgcn_mfma_f32_16x16x32_bf16(dl, wfh, acc2[f], 0, 0, 0);
            }
        }
        // rotation-max: rows r = 4*lk+q, reduce 4 regs + across lk groups
        #pragma unroll
        for (int f = 0; f < 4; ++f) {
            float mx = fmaxf(fmaxf(acc2[f][0], acc2[f][1]), fmaxf(acc2[f][2], acc2[f][3]));
            mx = fmaxf(mx, __shfl_xor(mx, 16));
            mx = fmaxf(mx, __shfl_xor(mx, 32));
            if (lk == 0) x_s[f * NG + hcol] = mx;
        }
    }
    __syncthreads();

    // ---- bias + BN + relu ----
    {
        const float cm = x_s[t] + b_conv[t];
        const float xv = (cm - bn_mean[t]) * rsqrtf(bn_var[t] + 1e-3f) * bn_gamma[t] + bn_beta[t];
        const float xr = fmaxf(xv, 0.0f);
        __syncthreads();
        x_s[t] = xr;
    }
    __syncthreads();

    // ---- d1: 320->80 relu, parallel over 320 threads (4 partials x 80 h) ----
    {
        const int part = t / NG;
        const int h    = t - part * NG;
        const int ib   = part * NG;
        float a = 0.0f;
        #pragma unroll 8
        for (int i2 = 0; i2 < NG; ++i2)
            a = fmaf(x_s[ib + i2], d1_w[(size_t)(ib + i2) * NG + h], a);
        y1p[part * NG + h] = a;
    }
    __syncthreads();
    if (t < NG) {
        const float a = d1_b[t] + y1p[t] + y1p[NG + t] + y1p[2 * NG + t] + y1p[3 * NG + t];
        y1_s[t] = fmaxf(a, 0.0f);
    }
    __syncthreads();

    // ---- d2: 80->4 relu ----
    if (t < NF) {
        float a = d2_b[t];
        #pragma unroll 8
        for (int i = 0; i < NG; ++i)
            a = fmaf(y1_s[i], d2_w[(size_t)i * NF + t], a);
        a = fmaxf(a, 0.0f);
        if (MODE < 2) x_out[(size_t)bs * NF + t] = a;
        else          y2_s[t] = a;
    }

    if (MODE == 2) {
        __syncthreads();
        if (t < 16) {
            float a = d3_b[t];
            #pragma unroll
            for (int ff = 0; ff < NF; ++ff)
                a = fmaf(y2_s[ff], d3_w[ff * 16 + t], a);
            y3_s[t] = fmaxf(a, 0.0f);
        }
        __syncthreads();
        if (t == 0) {
            float a = out_b[0];
            #pragma unroll
            for (int k = 0; k < 16; ++k)
                a = fmaf(y3_s[k], out_w[k], a);
            x_out[bs] = a;
        }
    }
}

extern "C" void kernel_launch(void* const* d_in, const int* in_sizes, int n_in,
                              void* d_out, int out_size, void* d_ws, size_t ws_size,
                              hipStream_t stream) {
    const float* input_feat  = (const float*)d_in[0];
    const float* rho         = (const float*)d_in[1];
    const float* theta       = (const float*)d_in[2];
    const float* mask        = (const float*)d_in[3];
    const float* mu_rho      = (const float*)d_in[4];
    const float* sigma_rho   = (const float*)d_in[6];
    const float* sigma_theta = (const float*)d_in[7];
    const float* W_conv      = (const float*)d_in[8];
    const float* b_conv      = (const float*)d_in[9];
    const float* bn_gamma    = (const float*)d_in[10];
    const float* bn_beta     = (const float*)d_in[11];
    const float* bn_mean     = (const float*)d_in[12];
    const float* bn_var      = (const float*)d_in[13];
    const float* d1_w        = (const float*)d_in[14];
    const float* d1_b        = (const float*)d_in[15];
    const float* d2_w        = (const float*)d_in[16];
    const float* d2_b        = (const float*)d_in[17];
    const float* d3_w        = (const float*)d_in[18];
    const float* d3_b        = (const float*)d_in[19];
    const float* out_w       = (const float*)d_in[20];
    const float* out_b       = (const float*)d_in[21];
    const int*   indices     = (const int*)d_in[22];

    float* x1  = (float*)d_ws;
    float* x2  = x1 + (size_t)NB * NS * NF;
    float* out = (float*)d_out;

    dim3 grid(NB * NS), block(NFG);

    masif_block_kernel<0><<<grid, block, 0, stream>>>(
        input_feat, rho, theta, mask, mu_rho, sigma_rho, sigma_theta,
        W_conv, b_conv, bn_gamma, bn_beta, bn_mean, bn_var,
        d1_w, d1_b, d2_w, d2_b, d3_w, d3_b, out_w, out_b, indices, nullptr, x1);

    masif_block_kernel<1><<<grid, block, 0, stream>>>(
        input_feat, rho, theta, mask, mu_rho, sigma_rho, sigma_theta,
        W_conv, b_conv, bn_gamma, bn_beta, bn_mean, bn_var,
        d1_w, d1_b, d2_w, d2_b, d3_w, d3_b, out_w, out_b, indices, x1, x2);

    masif_block_kernel<2><<<grid, block, 0, stream>>>(
        input_feat, rho, theta, mask, mu_rho, sigma_rho, sigma_theta,
        W_conv, b_conv, bn_gamma, bn_beta, bn_mean, bn_var,
        d1_w, d1_b, d2_w, d2_b, d3_w, d3_b, out_w, out_b, indices, x2, out);
}

// Round 5
// 216.531 us; speedup vs baseline: 6.1809x; 1.2791x over previous
//
#include <hip/hip_runtime.h>
#include <math.h>

#define NB 4
#define NS 256
#define NV 200
#define NVP 224
#define NF 4
#define NG 80
#define NFG 320
#define NROT 16
#define TWO_PI_F 6.28318530717958647692f
#define DELTA_F 0.39269908169872414f      // 2pi/16
#define INV_DELTA_F 2.5464790894703254f   // 16/2pi

#define AFE_ROW 248     // u16
#define T_ROW 31        // u32
#define NTROW 201       // 200 vertices + zero row
#define D_ROW 26        // f32
#define DESC_ROW 104    // u16

// reg0: T32 u32 [201][31] = 24924 | D_s f32 [256][26] = 26624 | x-block 2960  -> 26624
// reg1: afe 2*26*248*2 = 25792   | desc 2*64*104*2 = 26624                   -> 26624
#define REG0_BYTES 26624
#define REG1_BYTES 26624
// total 26624+26624+208 = 53456 -> rounds to 54272 <= 163840/3  => 3 blocks/CU

#define WT_ELEMS (4 * 80 * 96)   // 30720

typedef __attribute__((ext_vector_type(8))) short short8v;   // 8 bf16
typedef __attribute__((ext_vector_type(4))) float floatx4;   // MFMA acc
typedef __attribute__((ext_vector_type(4))) unsigned int uintx4;

__device__ __forceinline__ short8v mk_frag(unsigned a, unsigned b, unsigned c, unsigned d) {
    uintx4 v = {a, b, c, d};
    return __builtin_bit_cast(short8v, v);
}

// Pre-pack W^T into split-bf16: Wh/Wl[f][h][g] (g padded to 96), g<80 from W[f][g][h]
__global__ __launch_bounds__(256) void prep_w_kernel(
    const float* __restrict__ W, unsigned short* __restrict__ Wh, unsigned short* __restrict__ Wl)
{
    const int e = blockIdx.x * 256 + threadIdx.x;
    if (e >= WT_ELEMS) return;
    const int f   = e / 7680;
    const int rem = e - f * 7680;
    const int h   = rem / 96;
    const int g   = rem - h * 96;
    float v = 0.0f;
    if (g < NG) v = W[((size_t)(f * NG + g)) * NG + h];
    const unsigned u  = __float_as_uint(v);
    const unsigned hb = u & 0xffff0000u;
    const float    lo = v - __uint_as_float(hb);
    Wh[e] = (unsigned short)(u >> 16);
    Wl[e] = (unsigned short)(__float_as_uint(lo) >> 16);
}

template<int MODE>
__global__ __launch_bounds__(NFG, 3) void masif_block_kernel(
    const float* __restrict__ input_feat,
    const float* __restrict__ rho,
    const float* __restrict__ theta,
    const float* __restrict__ mask,
    const float* __restrict__ mu_rho,
    const float* __restrict__ sigma_rho,
    const float* __restrict__ sigma_theta,
    const float* __restrict__ W_conv,
    const unsigned short* __restrict__ Wt_h,
    const unsigned short* __restrict__ Wt_l,
    const float* __restrict__ b_conv,
    const float* __restrict__ bn_gamma,
    const float* __restrict__ bn_beta,
    const float* __restrict__ bn_mean,
    const float* __restrict__ bn_var,
    const float* __restrict__ d1_w,
    const float* __restrict__ d1_b,
    const float* __restrict__ d2_w,
    const float* __restrict__ d2_b,
    const float* __restrict__ d3_w,
    const float* __restrict__ d3_b,
    const float* __restrict__ out_w,
    const float* __restrict__ out_b,
    const int*   __restrict__ indices,
    const float* __restrict__ x_in,
    float*       __restrict__ x_out)
{
    const int bs = blockIdx.x;
    const int t  = threadIdx.x;
    const int lane = t & 63;
    const int lr   = lane & 15;
    const int lk   = lane >> 4;
    const int wv   = t >> 6;          // wave 0..4

    __shared__ __align__(16) char reg0[REG0_BYTES];
    __shared__ __align__(16) char reg1[REG1_BYTES];
    __shared__ unsigned char q_s8[208];

    unsigned int*   T32    = (unsigned int*)reg0;            // [201][31]
    float*          D_s    = (float*)reg0;                   // [256][26]
    float*          x_s    = (float*)reg0;                   // [320]  (post-stage3)
    float*          y1p    = x_s + NFG;                      // [320]
    float*          y1_s   = y1p + NFG;                      // [80]
    float*          y2_s   = y1_s + NG;                      // [4]
    float*          y3_s   = y2_s + NF;                      // [16]
    unsigned short* afe_h  = (unsigned short*)reg1;          // [26][248]
    unsigned short* afe_l  = afe_h + 26 * AFE_ROW;
    unsigned short* desc_h = (unsigned short*)reg1;          // [64][104]
    unsigned short* desc_l = desc_h + 4 * 16 * DESC_ROW;

    const int base = bs * NV;
    const int b    = bs / NS;

    const float sr  = sigma_rho[0];
    const float st  = sigma_theta[0];
    const float isr = 1.0f / (sr * sr + 1e-5f);
    const float ist = 1.0f / (st * st + 1e-5f);

    // ---- merged phase A+B: per-vertex afe rows + T-table row (no intermediate barrier) ----
    if (t < NVP) {
        const int v = t;
        float rv = 0.0f, mv = 0.0f, thv = 0.0f;
        float4 fv = {0.f, 0.f, 0.f, 0.f};
        if (v < NV) {
            rv  = rho[base + v];
            mv  = mask[base + v];
            thv = theta[base + v];
            if (MODE == 0) {
                fv = *reinterpret_cast<const float4*>(&input_feat[(size_t)(base + v) * NF]);
            } else {
                const int idx = indices[base + v];
                fv = *reinterpret_cast<const float4*>(&x_in[(size_t)(b * NS + idx) * NF]);
            }
        }
        const float w5[5] = {mv, mv * fv.x, mv * fv.y, mv * fv.z, mv * fv.w};
        #pragma unroll
        for (int ri = 0; ri < 5; ++ri) {
            const float dr = rv - mu_rho[ri * 16];
            const float R  = __expf(-(dr * dr) * isr);
            #pragma unroll
            for (int fp = 0; fp < 5; ++fp) {
                const float val = w5[fp] * R;
                const unsigned u  = __float_as_uint(val);
                const unsigned hb = u & 0xffff0000u;
                const float    lo = val - __uint_as_float(hb);
                const int i = fp * 5 + ri;
                afe_h[i * AFE_ROW + v] = (unsigned short)(u >> 16);
                afe_l[i * AFE_ROW + v] = (unsigned short)(__float_as_uint(lo) >> 16);
            }
        }
        if (v < NV) {
            const float qf = floorf(thv * INV_DELTA_F);
            const float a  = fmaf(-qf, DELTA_F, thv);
            q_s8[v] = (unsigned char)(((int)qf) & 15);
            #pragma unroll 4
            for (int d = 0; d < T_ROW; ++d) {
                const float dt  = fmaf((float)(d - 15), DELTA_F, a);
                const float val = __expf(-(dt * dt) * ist);
                const unsigned u  = __float_as_uint(val);
                const unsigned hb = u & 0xffff0000u;
                const float    lo = val - __uint_as_float(hb);
                T32[v * T_ROW + d] = hb | (__float_as_uint(lo) >> 16);
            }
        } else if (v == NV) {
            q_s8[NV] = 0;
            #pragma unroll 4
            for (int d = 0; d < T_ROW; ++d) T32[NV * T_ROW + d] = 0;   // zero row
        }
    } else {
        for (int z = t - NVP; z < AFE_ROW; z += NFG - NVP) {
            afe_h[25 * AFE_ROW + z] = 0;
            afe_l[25 * AFE_ROW + z] = 0;
        }
    }
    __syncthreads();

    // ---- stage 1: D[j=(r,ti)][i] = sum_v Tang[j,v]*Afe[i,v]; barrier-free K-loop ----
    floatx4 acc[7];
    #pragma unroll
    for (int ci = 0; ci < 7; ++ci) acc[ci] = floatx4{0.f, 0.f, 0.f, 0.f};

    const int i1c = (16 + lr) <= 24 ? (16 + lr) : 25;   // clamped B row for nt=1

    for (int kb = 0; kb < 7; ++kb) {
        const int vb = kb * 32 + 8 * lk;
        unsigned q8[8]; int tb[8];
        #pragma unroll
        for (int e = 0; e < 8; ++e) {
            const int vm = (vb + e) < NV ? (vb + e) : NV;   // clamp to zero row
            q8[e] = q_s8[vm];
            tb[e] = vm * T_ROW + 15 - lr;
        }
        const int co = vb;
        const short8v bh0 = *(const short8v*)&afe_h[lr * AFE_ROW + co];
        const short8v bl0 = *(const short8v*)&afe_l[lr * AFE_ROW + co];
        const short8v bh1 = *(const short8v*)&afe_h[i1c * AFE_ROW + co];
        const short8v bl1 = *(const short8v*)&afe_l[i1c * AFE_ROW + co];

        #pragma unroll
        for (int ci = 0; ci < 7; ++ci) {
            const int tile = wv + 5 * ci;
            if (tile < 32) {
                const int mt = tile >> 1;   // rotation r
                unsigned hp[4], lp[4];
                #pragma unroll
                for (int w2 = 0; w2 < 4; ++w2) {
                    const unsigned u0 = T32[tb[2 * w2]     + (int)((q8[2 * w2]     + mt) & 15u)];
                    const unsigned u1 = T32[tb[2 * w2 + 1] + (int)((q8[2 * w2 + 1] + mt) & 15u)];
                    hp[w2] = __builtin_amdgcn_perm(u1, u0, 0x07060302u);  // hi(e0)|hi(e1)
                    lp[w2] = __builtin_amdgcn_perm(u1, u0, 0x05040100u);  // lo(e0)|lo(e1)
                }
                const short8v ah = mk_frag(hp[0], hp[1], hp[2], hp[3]);
                const short8v al = mk_frag(lp[0], lp[1], lp[2], lp[3]);
                const short8v bh = (tile & 1) ? bh1 : bh0;
                const short8v bl = (tile & 1) ? bl1 : bl0;
                acc[ci] = __builtin_amdgcn_mfma_f32_16x16x32_bf16(ah, bh, acc[ci], 0, 0, 0);
                acc[ci] = __builtin_amdgcn_mfma_f32_16x16x32_bf16(ah, bl, acc[ci], 0, 0, 0);
                acc[ci] = __builtin_amdgcn_mfma_f32_16x16x32_bf16(al, bh, acc[ci], 0, 0, 0);
            }
        }
    }
    __syncthreads();   // all reads of T32/afe done

    // ---- write D_s [256][26] over T region ----
    #pragma unroll
    for (int ci = 0; ci < 7; ++ci) {
        const int tile = wv + 5 * ci;
        if (tile < 32) {
            const int mt = tile >> 1;
            const int nt = tile & 1;
            const int i  = 16 * nt + lr;
            if (i < 25) {
                #pragma unroll
                for (int q = 0; q < 4; ++q)
                    D_s[(16 * mt + 4 * lk + q) * D_ROW + i] = acc[ci][q];
            }
        }
    }
    __syncthreads();

    // ---- desc[f][r][g] = num/(den+eps), split-bf16 (overwrites afe region) ----
    for (int e = t; e < 4 * 16 * 96; e += NFG) {
        const int f   = e / 1536;
        const int rem = e - f * 1536;
        const int r   = rem / 96;
        const int g   = rem - r * 96;
        float dv = 0.0f;
        if (g < NG) {
            const int ti = g & 15, ri = g >> 4;
            const int j  = r * 16 + ti;
            const float den = D_s[j * D_ROW + ri];
            const float num = D_s[j * D_ROW + (f + 1) * 5 + ri];
            dv = __fdividef(num, den + 1e-5f);
        }
        const unsigned u  = __float_as_uint(dv);
        const unsigned hb = u & 0xffff0000u;
        const float    lo = dv - __uint_as_float(hb);
        desc_h[(f * 16 + r) * DESC_ROW + g] = (unsigned short)(u >> 16);
        desc_l[(f * 16 + r) * DESC_ROW + g] = (unsigned short)(__float_as_uint(lo) >> 16);
    }
    __syncthreads();

    // ---- stage 3: conv as MFMA. C[r][h] = sum_g desc[f][r][g]*W[f][g][h]; wave wv owns h-tile ----
    {
        const int hcol = 16 * wv + lr;   // 0..79
        const bool useWt = (Wt_h != nullptr);
        floatx4 acc2[4];
        #pragma unroll
        for (int f = 0; f < 4; ++f) acc2[f] = floatx4{0.f, 0.f, 0.f, 0.f};

        #pragma unroll
        for (int f = 0; f < 4; ++f) {
            #pragma unroll
            for (int ks = 0; ks < 3; ++ks) {
                const int g0 = ks * 32 + 8 * lk;
                short8v wfh, wfl;
                if (useWt) {
                    const size_t wo = (size_t)(f * NG + hcol) * 96 + g0;
                    wfh = *(const short8v*)&Wt_h[wo];
                    wfl = *(const short8v*)&Wt_l[wo];
                } else {
                    unsigned wh[4], wl[4];
                    #pragma unroll
                    for (int w2 = 0; w2 < 4; ++w2) {
                        const int ga = g0 + 2 * w2, gb = ga + 1;
                        float v0 = 0.f, v1 = 0.f;
                        if (ga < NG) v0 = W_conv[((size_t)(f * NG + ga)) * NG + hcol];
                        if (gb < NG) v1 = W_conv[((size_t)(f * NG + gb)) * NG + hcol];
                        const unsigned ua  = __float_as_uint(v0);
                        const unsigned ha  = ua & 0xffff0000u;
                        const float    la  = v0 - __uint_as_float(ha);
                        const unsigned ub  = __float_as_uint(v1);
                        const unsigned hb2 = ub & 0xffff0000u;
                        const float    lb  = v1 - __uint_as_float(hb2);
                        wh[w2] = (ua >> 16) | hb2;
                        wl[w2] = (__float_as_uint(la) >> 16) | (__float_as_uint(lb) & 0xffff0000u);
                    }
                    wfh = mk_frag(wh[0], wh[1], wh[2], wh[3]);
                    wfl = mk_frag(wl[0], wl[1], wl[2], wl[3]);
                }
                const int db = (f * 16 + lr) * DESC_ROW + g0;
                const short8v dh = *(const short8v*)&desc_h[db];
                const short8v dl = *(const short8v*)&desc_l[db];
                acc2[f] = __builtin_amdgcn_mfma_f32_16x16x32_bf16(dh, wfh, acc2[f], 0, 0, 0);
                acc2[f] = __builtin_amdgcn_mfma_f32_16x16x32_bf16(dh, wfl, acc2[f], 0, 0, 0);
                acc2[f] = __builtin_amdgcn_mfma_f32_16x16x32_bf16(dl, wfh, acc2[f], 0, 0, 0);
            }
        }
        __syncthreads();   // desc reads done; reg0 (D_s) dead -> x_s reuse safe
        #pragma unroll
        for (int f = 0; f < 4; ++f) {
            float mx = fmaxf(fmaxf(acc2[f][0], acc2[f][1]), fmaxf(acc2[f][2], acc2[f][3]));
            mx = fmaxf(mx, __shfl_xor(mx, 16));
            mx = fmaxf(mx, __shfl_xor(mx, 32));
            if (lk == 0) x_s[f * NG + hcol] = mx;
        }
    }
    __syncthreads();

    // ---- bias + BN + relu ----
    {
        const float cm = x_s[t] + b_conv[t];
        const float xv = (cm - bn_mean[t]) * rsqrtf(bn_var[t] + 1e-3f) * bn_gamma[t] + bn_beta[t];
        x_s[t] = fmaxf(xv, 0.0f);   // same slot read->write by same thread; no barrier needed
    }
    __syncthreads();

    // ---- d1: 320->80 relu (4 partials x 80 h) ----
    {
        const int part = t / NG;
        const int h    = t - part * NG;
        const int ib   = part * NG;
        float a = 0.0f;
        #pragma unroll 8
        for (int i2 = 0; i2 < NG; ++i2)
            a = fmaf(x_s[ib + i2], d1_w[(size_t)(ib + i2) * NG + h], a);
        y1p[part * NG + h] = a;
    }
    __syncthreads();
    if (t < NG) {
        const float a = d1_b[t] + y1p[t] + y1p[NG + t] + y1p[2 * NG + t] + y1p[3 * NG + t];
        y1_s[t] = fmaxf(a, 0.0f);
    }
    __syncthreads();

    // ---- d2: 80->4 relu ----
    if (t < NF) {
        float a = d2_b[t];
        #pragma unroll 8
        for (int i = 0; i < NG; ++i)
            a = fmaf(y1_s[i], d2_w[(size_t)i * NF + t], a);
        a = fmaxf(a, 0.0f);
        if (MODE < 2) x_out[(size_t)bs * NF + t] = a;
        else          y2_s[t] = a;
    }

    if (MODE == 2) {
        __syncthreads();
        if (t < 16) {
            float a = d3_b[t];
            #pragma unroll
            for (int ff = 0; ff < NF; ++ff)
                a = fmaf(y2_s[ff], d3_w[ff * 16 + t], a);
            y3_s[t] = fmaxf(a, 0.0f);
        }
        __syncthreads();
        if (t == 0) {
            float a = out_b[0];
            #pragma unroll
            for (int k = 0; k < 16; ++k)
                a = fmaf(y3_s[k], out_w[k], a);
            x_out[bs] = a;
        }
    }
}

extern "C" void kernel_launch(void* const* d_in, const int* in_sizes, int n_in,
                              void* d_out, int out_size, void* d_ws, size_t ws_size,
                              hipStream_t stream) {
    const float* input_feat  = (const float*)d_in[0];
    const float* rho         = (const float*)d_in[1];
    const float* theta       = (const float*)d_in[2];
    const float* mask        = (const float*)d_in[3];
    const float* mu_rho      = (const float*)d_in[4];
    const float* sigma_rho   = (const float*)d_in[6];
    const float* sigma_theta = (const float*)d_in[7];
    const float* W_conv      = (const float*)d_in[8];
    const float* b_conv      = (const float*)d_in[9];
    const float* bn_gamma    = (const float*)d_in[10];
    const float* bn_beta     = (const float*)d_in[11];
    const float* bn_mean     = (const float*)d_in[12];
    const float* bn_var      = (const float*)d_in[13];
    const float* d1_w        = (const float*)d_in[14];
    const float* d1_b        = (const float*)d_in[15];
    const float* d2_w        = (const float*)d_in[16];
    const float* d2_b        = (const float*)d_in[17];
    const float* d3_w        = (const float*)d_in[18];
    const float* d3_b        = (const float*)d_in[19];
    const float* out_w       = (const float*)d_in[20];
    const float* out_b       = (const float*)d_in[21];
    const int*   indices     = (const int*)d_in[22];

    float* x1  = (float*)d_ws;                 // [4096] f32
    float* x2  = x1 + (size_t)NB * NS * NF;    // [4096] f32
    float* out = (float*)d_out;

    const size_t WT_OFF   = 32768;
    const size_t WT_BYTES = (size_t)2 * WT_ELEMS * 2;   // 122880
    unsigned short* Wh = nullptr;
    unsigned short* Wl = nullptr;
    if (ws_size >= WT_OFF + WT_BYTES) {
        Wh = (unsigned short*)((char*)d_ws + WT_OFF);
        Wl = Wh + WT_ELEMS;
        prep_w_kernel<<<(WT_ELEMS + 255) / 256, 256, 0, stream>>>(W_conv, Wh, Wl);
    }

    dim3 grid(NB * NS), block(NFG);

    masif_block_kernel<0><<<grid, block, 0, stream>>>(
        input_feat, rho, theta, mask, mu_rho, sigma_rho, sigma_theta,
        W_conv, Wh, Wl, b_conv, bn_gamma, bn_beta, bn_mean, bn_var,
        d1_w, d1_b, d2_w, d2_b, d3_w, d3_b, out_w, out_b, indices, nullptr, x1);

    masif_block_kernel<1><<<grid, block, 0, stream>>>(
        input_feat, rho, theta, mask, mu_rho, sigma_rho, sigma_theta,
        W_conv, Wh, Wl, b_conv, bn_gamma, bn_beta, bn_mean, bn_var,
        d1_w, d1_b, d2_w, d2_b, d3_w, d3_b, out_w, out_b, indices, x1, x2);

    masif_block_kernel<2><<<grid, block, 0, stream>>>(
        input_feat, rho, theta, mask, mu_rho, sigma_rho, sigma_theta,
        W_conv, Wh, Wl, b_conv, bn_gamma, bn_beta, bn_mean, bn_var,
        d1_w, d1_b, d2_w, d2_b, d3_w, d3_b, out_w, out_b, indices, x2, out);
}

// Round 6
// 151.410 us; speedup vs baseline: 8.8392x; 1.4301x over previous
//
#include <hip/hip_runtime.h>
#include <math.h>

#define NB 4
#define NS 256
#define NV 200
#define NVP 224
#define NF 4
#define NG 80
#define NFG 320
#define NROT 16
#define TWO_PI_F 6.28318530717958647692f
#define DELTA_F 0.39269908169872414f      // 2pi/16
#define INV_DELTA_F 2.5464790894703254f   // 16/2pi

#define AFE_ROW 248     // u16
#define T_ROW 31        // u16 (bf16 RNE, no lo part)
#define D_ROW 27        // f32, odd so lane stride 27 hits 16 distinct banks

// smem layout (union, 16B aligned base):
//   Phase A..stage1:  [0,12464)            T16 u16 [201][31]  (12462B)
//                     [12464, 38256)       afe_h|afe_l u16 [26][248] each (25792B)
//   Post-stage1:      [0, 27648)           D_s f32 [256][27]   (row j' = ti*16 + r)
//                     [27648, 30608)       x_s[320]|y1p[320]|y1_s[80]|y2[4]|y3[16] f32
#define SMEM_BYTES 38256
// + q_s8[208]  => ~38.5KB => 4 blocks/CU (163840/4 = 40960)

#define WT_ELEMS (4 * 80 * 96)   // 30720

typedef __attribute__((ext_vector_type(8))) short short8v;   // 8 bf16
typedef __attribute__((ext_vector_type(4))) float floatx4;   // MFMA acc
typedef __attribute__((ext_vector_type(4))) unsigned int uintx4;

__device__ __forceinline__ short8v mk_frag(unsigned a, unsigned b, unsigned c, unsigned d) {
    uintx4 v = {a, b, c, d};
    return __builtin_bit_cast(short8v, v);
}

// Pre-pack W^T into split-bf16: Wh/Wl[f][h][g] (g padded to 96), g<80 from W[f][g][h]
__global__ __launch_bounds__(256) void prep_w_kernel(
    const float* __restrict__ W, unsigned short* __restrict__ Wh, unsigned short* __restrict__ Wl)
{
    const int e = blockIdx.x * 256 + threadIdx.x;
    if (e >= WT_ELEMS) return;
    const int f   = e / 7680;
    const int rem = e - f * 7680;
    const int h   = rem / 96;
    const int g   = rem - h * 96;
    float v = 0.0f;
    if (g < NG) v = W[((size_t)(f * NG + g)) * NG + h];
    const unsigned u  = __float_as_uint(v);
    const unsigned hb = u & 0xffff0000u;
    const float    lo = v - __uint_as_float(hb);
    Wh[e] = (unsigned short)(u >> 16);
    Wl[e] = (unsigned short)(__float_as_uint(lo) >> 16);
}

template<int MODE>
__global__ __launch_bounds__(NFG, 5) void masif_block_kernel(
    const float* __restrict__ input_feat,
    const float* __restrict__ rho,
    const float* __restrict__ theta,
    const float* __restrict__ mask,
    const float* __restrict__ mu_rho,
    const float* __restrict__ sigma_rho,
    const float* __restrict__ sigma_theta,
    const float* __restrict__ W_conv,
    const unsigned short* __restrict__ Wt_h,
    const unsigned short* __restrict__ Wt_l,
    const float* __restrict__ b_conv,
    const float* __restrict__ bn_gamma,
    const float* __restrict__ bn_beta,
    const float* __restrict__ bn_mean,
    const float* __restrict__ bn_var,
    const float* __restrict__ d1_w,
    const float* __restrict__ d1_b,
    const float* __restrict__ d2_w,
    const float* __restrict__ d2_b,
    const float* __restrict__ d3_w,
    const float* __restrict__ d3_b,
    const float* __restrict__ out_w,
    const float* __restrict__ out_b,
    const int*   __restrict__ indices,
    const float* __restrict__ x_in,
    float*       __restrict__ x_out)
{
    const int bs = blockIdx.x;
    const int t  = threadIdx.x;
    const int lane = t & 63;
    const int lr   = lane & 15;
    const int lk   = lane >> 4;
    const int wv   = t >> 6;          // wave 0..4

    __shared__ __align__(16) char smem[SMEM_BYTES];
    __shared__ unsigned char q_s8[208];

    unsigned short* T16   = (unsigned short*)smem;                 // [201][31]
    unsigned short* afe_h = (unsigned short*)(smem + 12464);       // [26][248]
    unsigned short* afe_l = afe_h + 26 * AFE_ROW;
    float*          D_s   = (float*)smem;                          // [256][27], row = ti*16 + r
    float*          x_s   = (float*)(smem + 27648);                // [320]
    float*          y1p   = x_s + NFG;                             // [320]
    float*          y1_s  = y1p + NFG;                             // [80]
    float*          y2_s  = y1_s + NG;                             // [4]
    float*          y3_s  = y2_s + NF;                             // [16]

    const int base = bs * NV;
    const int b    = bs / NS;

    const float sr  = sigma_rho[0];
    const float st  = sigma_theta[0];
    const float isr = 1.0f / (sr * sr + 1e-5f);
    const float ist = 1.0f / (st * st + 1e-5f);

    // ---- phase A+B: per-vertex afe rows (split-bf16) + T row (RNE bf16) ----
    if (t < NVP) {
        const int v = t;
        float rv = 0.0f, mv = 0.0f, thv = 0.0f;
        float4 fv = {0.f, 0.f, 0.f, 0.f};
        if (v < NV) {
            rv  = rho[base + v];
            mv  = mask[base + v];
            thv = theta[base + v];
            if (MODE == 0) {
                fv = *reinterpret_cast<const float4*>(&input_feat[(size_t)(base + v) * NF]);
            } else {
                const int idx = indices[base + v];
                fv = *reinterpret_cast<const float4*>(&x_in[(size_t)(b * NS + idx) * NF]);
            }
        }
        const float w5[5] = {mv, mv * fv.x, mv * fv.y, mv * fv.z, mv * fv.w};
        #pragma unroll
        for (int ri = 0; ri < 5; ++ri) {
            const float dr = rv - mu_rho[ri * 16];
            const float R  = __expf(-(dr * dr) * isr);
            #pragma unroll
            for (int fp = 0; fp < 5; ++fp) {
                const float val = w5[fp] * R;
                const unsigned u  = __float_as_uint(val);
                const unsigned hb = u & 0xffff0000u;
                const float    lo = val - __uint_as_float(hb);
                const int i = fp * 5 + ri;
                afe_h[i * AFE_ROW + v] = (unsigned short)(u >> 16);
                afe_l[i * AFE_ROW + v] = (unsigned short)(__float_as_uint(lo) >> 16);
            }
        }
        if (v < NV) {
            const float qf = floorf(thv * INV_DELTA_F);
            const float a  = fmaf(-qf, DELTA_F, thv);
            q_s8[v] = (unsigned char)(((int)qf) & 15);
            #pragma unroll 4
            for (int d = 0; d < T_ROW; ++d) {
                const float dt  = fmaf((float)(d - 15), DELTA_F, a);
                const float val = __expf(-(dt * dt) * ist);
                const unsigned u = __float_as_uint(val);
                const unsigned r = u + 0x7fffu + ((u >> 16) & 1u);   // RNE to bf16
                T16[v * T_ROW + d] = (unsigned short)(r >> 16);
            }
        } else if (v == NV) {
            q_s8[NV] = 0;
            #pragma unroll 4
            for (int d = 0; d < T_ROW; ++d) T16[NV * T_ROW + d] = 0;   // zero row
        }
    } else {
        for (int z = t - NVP; z < AFE_ROW; z += NFG - NVP) {
            afe_h[25 * AFE_ROW + z] = 0;
            afe_l[25 * AFE_ROW + z] = 0;
        }
    }
    __syncthreads();

    // ---- stage 1: D[j=(r,ti)][i] = sum_v Tang[j,v]*Afe[i,v]; barrier-free K-loop ----
    floatx4 acc[7];
    #pragma unroll
    for (int ci = 0; ci < 7; ++ci) acc[ci] = floatx4{0.f, 0.f, 0.f, 0.f};

    const int i1c = (16 + lr) <= 24 ? (16 + lr) : 25;   // clamped B row for nt=1

    for (int kb = 0; kb < 7; ++kb) {
        const int vb = kb * 32 + 8 * lk;
        unsigned q8[8]; int tb[8];
        #pragma unroll
        for (int e = 0; e < 8; ++e) {
            const int vm = (vb + e) < NV ? (vb + e) : NV;   // clamp to zero row
            q8[e] = q_s8[vm];
            tb[e] = vm * T_ROW + 15 - lr;
        }
        const int co = vb;
        const short8v bh0 = *(const short8v*)&afe_h[lr * AFE_ROW + co];
        const short8v bl0 = *(const short8v*)&afe_l[lr * AFE_ROW + co];
        const short8v bh1 = *(const short8v*)&afe_h[i1c * AFE_ROW + co];
        const short8v bl1 = *(const short8v*)&afe_l[i1c * AFE_ROW + co];

        #pragma unroll
        for (int ci = 0; ci < 7; ++ci) {
            const int tile = wv + 5 * ci;
            if (tile < 32) {
                const int mt = tile >> 1;   // rotation r
                unsigned hp[4];
                #pragma unroll
                for (int w2 = 0; w2 < 4; ++w2) {
                    const unsigned u0 = T16[tb[2 * w2]     + (int)((q8[2 * w2]     + mt) & 15u)];
                    const unsigned u1 = T16[tb[2 * w2 + 1] + (int)((q8[2 * w2 + 1] + mt) & 15u)];
                    hp[w2] = u0 | (u1 << 16);
                }
                const short8v ah = mk_frag(hp[0], hp[1], hp[2], hp[3]);
                const short8v bh = (tile & 1) ? bh1 : bh0;
                const short8v bl = (tile & 1) ? bl1 : bl0;
                acc[ci] = __builtin_amdgcn_mfma_f32_16x16x32_bf16(ah, bh, acc[ci], 0, 0, 0);
                acc[ci] = __builtin_amdgcn_mfma_f32_16x16x32_bf16(ah, bl, acc[ci], 0, 0, 0);
            }
        }
    }
    __syncthreads();   // all reads of T16/afe done

    // ---- write D_s [ti*16+r][27] over T/afe region ----
    #pragma unroll
    for (int ci = 0; ci < 7; ++ci) {
        const int tile = wv + 5 * ci;
        if (tile < 32) {
            const int mt = tile >> 1;          // r
            const int nt = tile & 1;
            const int i  = 16 * nt + lr;
            if (i < 25) {
                #pragma unroll
                for (int q = 0; q < 4; ++q) {
                    const int ti = 4 * lk + q;
                    D_s[(ti * 16 + mt) * D_ROW + i] = acc[ci][q];
                }
            }
        }
    }
    __syncthreads();

    // ---- stage 3: conv as MFMA with in-register desc. C[r][h] = sum_g desc[f][r][g]*W[f][g][h] ----
    {
        const int hcol = 16 * wv + lr;   // 0..79 (wave wv owns h-tile)
        const bool useWt = (Wt_h != nullptr);
        floatx4 acc2[4];
        #pragma unroll
        for (int f = 0; f < 4; ++f) acc2[f] = floatx4{0.f, 0.f, 0.f, 0.f};

        #pragma unroll
        for (int ks = 0; ks < 3; ++ks) {
            const int g0 = ks * 32 + 8 * lk;
            // reciprocal of den, shared across f (A-row r = lr)
            float rden[8];
            #pragma unroll
            for (int e = 0; e < 8; ++e) {
                const int g = g0 + e;
                if (g < NG) {
                    const int ti = g & 15, ri = g >> 4;
                    rden[e] = __builtin_amdgcn_rcpf(D_s[(ti * 16 + lr) * D_ROW + ri] + 1e-5f);
                } else rden[e] = 0.0f;
            }
            #pragma unroll
            for (int f = 0; f < 4; ++f) {
                short8v wfh, wfl;
                if (useWt) {
                    const size_t wo = (size_t)(f * NG + hcol) * 96 + g0;
                    wfh = *(const short8v*)&Wt_h[wo];
                    wfl = *(const short8v*)&Wt_l[wo];
                } else {
                    unsigned wh[4], wl[4];
                    #pragma unroll
                    for (int w2 = 0; w2 < 4; ++w2) {
                        const int ga = g0 + 2 * w2, gb = ga + 1;
                        float v0 = 0.f, v1 = 0.f;
                        if (ga < NG) v0 = W_conv[((size_t)(f * NG + ga)) * NG + hcol];
                        if (gb < NG) v1 = W_conv[((size_t)(f * NG + gb)) * NG + hcol];
                        const unsigned ua  = __float_as_uint(v0);
                        const unsigned ha  = ua & 0xffff0000u;
                        const float    la  = v0 - __uint_as_float(ha);
                        const unsigned ub  = __float_as_uint(v1);
                        const unsigned hb2 = ub & 0xffff0000u;
                        const float    lb  = v1 - __uint_as_float(hb2);
                        wh[w2] = (ua >> 16) | hb2;
                        wl[w2] = (__float_as_uint(la) >> 16) | (__float_as_uint(lb) & 0xffff0000u);
                    }
                    wfh = mk_frag(wh[0], wh[1], wh[2], wh[3]);
                    wfl = mk_frag(wl[0], wl[1], wl[2], wl[3]);
                }
                // desc fragment in-register: dv = num * rden
                unsigned dh[4], dl[4];
                #pragma unroll
                for (int w2 = 0; w2 < 4; ++w2) {
                    float pv[2];
                    #pragma unroll
                    for (int p = 0; p < 2; ++p) {
                        const int e = 2 * w2 + p;
                        const int g = g0 + e;
                        float dv = 0.0f;
                        if (g < NG) {
                            const int ti = g & 15, ri = g >> 4;
                            dv = D_s[(ti * 16 + lr) * D_ROW + (f + 1) * 5 + ri] * rden[e];
                        }
                        pv[p] = dv;
                    }
                    const unsigned ua = __float_as_uint(pv[0]);
                    const unsigned ha = ua & 0xffff0000u;
                    const float    la = pv[0] - __uint_as_float(ha);
                    const unsigned ub = __float_as_uint(pv[1]);
                    const unsigned hb2 = ub & 0xffff0000u;
                    const float    lb = pv[1] - __uint_as_float(hb2);
                    dh[w2] = (ua >> 16) | hb2;
                    dl[w2] = (__float_as_uint(la) >> 16) | (__float_as_uint(lb) & 0xffff0000u);
                }
                const short8v dhv = mk_frag(dh[0], dh[1], dh[2], dh[3]);
                const short8v dlv = mk_frag(dl[0], dl[1], dl[2], dl[3]);
                acc2[f] = __builtin_amdgcn_mfma_f32_16x16x32_bf16(dhv, wfh, acc2[f], 0, 0, 0);
                acc2[f] = __builtin_amdgcn_mfma_f32_16x16x32_bf16(dhv, wfl, acc2[f], 0, 0, 0);
                acc2[f] = __builtin_amdgcn_mfma_f32_16x16x32_bf16(dlv, wfh, acc2[f], 0, 0, 0);
            }
        }
        __syncthreads();   // D_s reads done
        #pragma unroll
        for (int f = 0; f < 4; ++f) {
            float mx = fmaxf(fmaxf(acc2[f][0], acc2[f][1]), fmaxf(acc2[f][2], acc2[f][3]));
            mx = fmaxf(mx, __shfl_xor(mx, 16));
            mx = fmaxf(mx, __shfl_xor(mx, 32));
            if (lk == 0) x_s[f * NG + hcol] = mx;
        }
    }
    __syncthreads();

    // ---- bias + BN + relu ----
    {
        const float cm = x_s[t] + b_conv[t];
        const float xv = (cm - bn_mean[t]) * rsqrtf(bn_var[t] + 1e-3f) * bn_gamma[t] + bn_beta[t];
        x_s[t] = fmaxf(xv, 0.0f);
    }
    __syncthreads();

    // ---- d1: 320->80 relu (4 partials x 80 h) ----
    {
        const int part = t / NG;
        const int h    = t - part * NG;
        const int ib   = part * NG;
        float a = 0.0f;
        #pragma unroll 8
        for (int i2 = 0; i2 < NG; ++i2)
            a = fmaf(x_s[ib + i2], d1_w[(size_t)(ib + i2) * NG + h], a);
        y1p[part * NG + h] = a;
    }
    __syncthreads();
    if (t < NG) {
        const float a = d1_b[t] + y1p[t] + y1p[NG + t] + y1p[2 * NG + t] + y1p[3 * NG + t];
        y1_s[t] = fmaxf(a, 0.0f);
    }
    __syncthreads();

    // ---- d2: 80->4 relu ----
    if (t < NF) {
        float a = d2_b[t];
        #pragma unroll 8
        for (int i = 0; i < NG; ++i)
            a = fmaf(y1_s[i], d2_w[(size_t)i * NF + t], a);
        a = fmaxf(a, 0.0f);
        if (MODE < 2) x_out[(size_t)bs * NF + t] = a;
        else          y2_s[t] = a;
    }

    if (MODE == 2) {
        __syncthreads();
        if (t < 16) {
            float a = d3_b[t];
            #pragma unroll
            for (int ff = 0; ff < NF; ++ff)
                a = fmaf(y2_s[ff], d3_w[ff * 16 + t], a);
            y3_s[t] = fmaxf(a, 0.0f);
        }
        __syncthreads();
        if (t == 0) {
            float a = out_b[0];
            #pragma unroll
            for (int k = 0; k < 16; ++k)
                a = fmaf(y3_s[k], out_w[k], a);
            x_out[bs] = a;
        }
    }
}

extern "C" void kernel_launch(void* const* d_in, const int* in_sizes, int n_in,
                              void* d_out, int out_size, void* d_ws, size_t ws_size,
                              hipStream_t stream) {
    const float* input_feat  = (const float*)d_in[0];
    const float* rho         = (const float*)d_in[1];
    const float* theta       = (const float*)d_in[2];
    const float* mask        = (const float*)d_in[3];
    const float* mu_rho      = (const float*)d_in[4];
    const float* sigma_rho   = (const float*)d_in[6];
    const float* sigma_theta = (const float*)d_in[7];
    const float* W_conv      = (const float*)d_in[8];
    const float* b_conv      = (const float*)d_in[9];
    const float* bn_gamma    = (const float*)d_in[10];
    const float* bn_beta     = (const float*)d_in[11];
    const float* bn_mean     = (const float*)d_in[12];
    const float* bn_var      = (const float*)d_in[13];
    const float* d1_w        = (const float*)d_in[14];
    const float* d1_b        = (const float*)d_in[15];
    const float* d2_w        = (const float*)d_in[16];
    const float* d2_b        = (const float*)d_in[17];
    const float* d3_w        = (const float*)d_in[18];
    const float* d3_b        = (const float*)d_in[19];
    const float* out_w       = (const float*)d_in[20];
    const float* out_b       = (const float*)d_in[21];
    const int*   indices     = (const int*)d_in[22];

    float* x1  = (float*)d_ws;                 // [4096] f32
    float* x2  = x1 + (size_t)NB * NS * NF;    // [4096] f32
    float* out = (float*)d_out;

    const size_t WT_OFF   = 32768;
    const size_t WT_BYTES = (size_t)2 * WT_ELEMS * 2;   // 122880
    unsigned short* Wh = nullptr;
    unsigned short* Wl = nullptr;
    if (ws_size >= WT_OFF + WT_BYTES) {
        Wh = (unsigned short*)((char*)d_ws + WT_OFF);
        Wl = Wh + WT_ELEMS;
        prep_w_kernel<<<(WT_ELEMS + 255) / 256, 256, 0, stream>>>(W_conv, Wh, Wl);
    }

    dim3 grid(NB * NS), block(NFG);

    masif_block_kernel<0><<<grid, block, 0, stream>>>(
        input_feat, rho, theta, mask, mu_rho, sigma_rho, sigma_theta,
        W_conv, Wh, Wl, b_conv, bn_gamma, bn_beta, bn_mean, bn_var,
        d1_w, d1_b, d2_w, d2_b, d3_w, d3_b, out_w, out_b, indices, nullptr, x1);

    masif_block_kernel<1><<<grid, block, 0, stream>>>(
        input_feat, rho, theta, mask, mu_rho, sigma_rho, sigma_theta,
        W_conv, Wh, Wl, b_conv, bn_gamma, bn_beta, bn_mean, bn_var,
        d1_w, d1_b, d2_w, d2_b, d3_w, d3_b, out_w, out_b, indices, x1, x2);

    masif_block_kernel<2><<<grid, block, 0, stream>>>(
        input_feat, rho, theta, mask, mu_rho, sigma_rho, sigma_theta,
        W_conv, Wh, Wl, b_conv, bn_gamma, bn_beta, bn_mean, bn_var,
        d1_w, d1_b, d2_w, d2_b, d3_w, d3_b, out_w, out_b, indices, x2, out);
}

// Round 7
// 120.742 us; speedup vs baseline: 11.0844x; 1.2540x over previous
//
#include <hip/hip_runtime.h>
#include <math.h>

#define NB 4
#define NS 256
#define NV 200
#define NVP 224
#define NF 4
#define NG 80
#define NFG 320
#define NROT 16
#define DELTA_F 0.39269908169872414f      // 2pi/16
#define INV_DELTA_F 2.5464790894703254f   // 16/2pi

#define SLOTS 248       // max padded slots: 200 + 16*3 = 248
#define T_ROWS 31
#define D_ROW 27        // f32, odd stride -> 16 distinct banks

// smem union:
//   pre-stage1: Tt u16[31][248] (15376B) | afe_h u16[25][248] (12400B) | afe_l (12400B) = 40176B
//   post-stage1: D_s f32[256][27] = 27648B ; x-block at 28672 (2960B)
#define TT_BYTES   (T_ROWS * SLOTS * 2)          // 15376
#define AFE_OFF    TT_BYTES
#define AFE_BYTES  (25 * SLOTS * 2)              // 12400
#define SMEM_BYTES (AFE_OFF + 2 * AFE_BYTES)     // 40176

#define WT_ELEMS (4 * 80 * 96)   // 30720

typedef __attribute__((ext_vector_type(8))) short short8v;   // 8 bf16
typedef __attribute__((ext_vector_type(4))) float floatx4;   // MFMA acc
typedef __attribute__((ext_vector_type(4))) unsigned int uintx4;

__device__ __forceinline__ short8v mk_frag(unsigned a, unsigned b, unsigned c, unsigned d) {
    uintx4 v = {a, b, c, d};
    return __builtin_bit_cast(short8v, v);
}

// Pre-pack W^T into split-bf16: Wh/Wl[f][h][g] (g padded to 96), g<80 from W[f][g][h]
__global__ __launch_bounds__(256) void prep_w_kernel(
    const float* __restrict__ W, unsigned short* __restrict__ Wh, unsigned short* __restrict__ Wl)
{
    const int e = blockIdx.x * 256 + threadIdx.x;
    if (e >= WT_ELEMS) return;
    const int f   = e / 7680;
    const int rem = e - f * 7680;
    const int h   = rem / 96;
    const int g   = rem - h * 96;
    float v = 0.0f;
    if (g < NG) v = W[((size_t)(f * NG + g)) * NG + h];
    const unsigned u  = __float_as_uint(v);
    const unsigned hb = u & 0xffff0000u;
    const float    lo = v - __uint_as_float(hb);
    Wh[e] = (unsigned short)(u >> 16);
    Wl[e] = (unsigned short)(__float_as_uint(lo) >> 16);
}

template<int MODE>
__global__ __launch_bounds__(NFG, 5) void masif_block_kernel(
    const float* __restrict__ input_feat,
    const float* __restrict__ rho,
    const float* __restrict__ theta,
    const float* __restrict__ mask,
    const float* __restrict__ mu_rho,
    const float* __restrict__ sigma_rho,
    const float* __restrict__ sigma_theta,
    const float* __restrict__ W_conv,
    const unsigned short* __restrict__ Wt_h,
    const unsigned short* __restrict__ Wt_l,
    const float* __restrict__ b_conv,
    const float* __restrict__ bn_gamma,
    const float* __restrict__ bn_beta,
    const float* __restrict__ bn_mean,
    const float* __restrict__ bn_var,
    const float* __restrict__ d1_w,
    const float* __restrict__ d1_b,
    const float* __restrict__ d2_w,
    const float* __restrict__ d2_b,
    const float* __restrict__ d3_w,
    const float* __restrict__ d3_b,
    const float* __restrict__ out_w,
    const float* __restrict__ out_b,
    const int*   __restrict__ indices,
    const float* __restrict__ x_in,
    float*       __restrict__ x_out)
{
    const int bs = blockIdx.x;
    const int t  = threadIdx.x;
    const int lane = t & 63;
    const int lr   = lane & 15;
    const int lk   = lane >> 4;
    const int wv   = t >> 6;          // wave 0..4

    __shared__ __align__(16) char smem[SMEM_BYTES];
    __shared__ unsigned short wcnt16[4 * 16];   // per-wave bucket counts
    __shared__ unsigned int   base_s[17];       // padded bucket bases; [16] = nslot
    __shared__ unsigned char  grpq[64];         // q per 4-slot group

    unsigned short* Tt    = (unsigned short*)smem;                 // [31][248]
    unsigned short* afe_h = (unsigned short*)(smem + AFE_OFF);     // [25][248]
    unsigned short* afe_l = afe_h + 25 * SLOTS;
    float*          D_s   = (float*)smem;                          // [256][27], row = ti*16 + r
    float*          x_s   = (float*)(smem + 28672);                // [320]
    float*          y1p   = x_s + NFG;                             // [320]
    float*          y1_s  = y1p + NFG;                             // [80]
    float*          y2_s  = y1_s + NG;                             // [4]
    float*          y3_s  = y2_s + NF;                             // [16]

    const int base = bs * NV;
    const int b    = bs / NS;

    const float sr  = sigma_rho[0];
    const float st  = sigma_theta[0];
    const float isr = 1.0f / (sr * sr + 1e-5f);
    const float ist = 1.0f / (st * st + 1e-5f);

    // ---- step0: zero Tt+afe; load per-vertex data; compute q; wave-ballot rank ----
    for (int off = t * 16; off < SMEM_BYTES; off += NFG * 16)
        *(uintx4*)(smem + off) = (uintx4){0u, 0u, 0u, 0u};

    const bool valid = (t < NV);
    float rv = 0.0f, mv = 0.0f, thv = 0.0f, av = 0.0f;
    float4 fv = {0.f, 0.f, 0.f, 0.f};
    int myq = 0, rank = 0;
    if (valid) {
        rv  = rho[base + t];
        mv  = mask[base + t];
        thv = theta[base + t];
        if (MODE == 0) {
            fv = *reinterpret_cast<const float4*>(&input_feat[(size_t)(base + t) * NF]);
        } else {
            const int idx = indices[base + t];
            fv = *reinterpret_cast<const float4*>(&x_in[(size_t)(b * NS + idx) * NF]);
        }
        const float qf = floorf(thv * INV_DELTA_F);
        av  = fmaf(-qf, DELTA_F, thv);
        myq = ((int)qf) & 15;
    }
    {
        unsigned long long mymask = 0ull;
        #pragma unroll
        for (int bq = 0; bq < 16; ++bq) {
            const unsigned long long m = __ballot(valid && (myq == bq));
            if (wv < 4 && lane == bq) wcnt16[wv * 16 + bq] = (unsigned short)__popcll(m);
            if (valid && myq == bq) mymask = m;
        }
        rank = (int)__popcll(mymask & ((1ull << lane) - 1ull));
    }
    __syncthreads();

    // ---- padded prefix (t==0) ----
    if (t == 0) {
        unsigned s = 0;
        #pragma unroll
        for (int bq = 0; bq < 16; ++bq) {
            base_s[bq] = s;
            unsigned c = (unsigned)wcnt16[bq] + wcnt16[16 + bq] + wcnt16[32 + bq] + wcnt16[48 + bq];
            s += (c + 3u) & ~3u;
        }
        base_s[16] = s;   // nslot (multiple of 4, <= 248)
    }
    __syncthreads();

    // ---- scatter: afe rows + transposed T at column slot ----
    if (valid) {
        int rk = rank;
        #pragma unroll
        for (int w = 0; w < 3; ++w)
            if (wv > w) rk += wcnt16[w * 16 + myq];
        const int slot = (int)base_s[myq] + rk;

        const float w5[5] = {mv, mv * fv.x, mv * fv.y, mv * fv.z, mv * fv.w};
        #pragma unroll
        for (int ri = 0; ri < 5; ++ri) {
            const float dr = rv - mu_rho[ri * 16];
            const float R  = __expf(-(dr * dr) * isr);
            #pragma unroll
            for (int fp = 0; fp < 5; ++fp) {
                const float val = w5[fp] * R;
                const unsigned u  = __float_as_uint(val);
                const unsigned hb = u & 0xffff0000u;
                const float    lo = val - __uint_as_float(hb);
                const int i = fp * 5 + ri;
                afe_h[i * SLOTS + slot] = (unsigned short)(u >> 16);
                afe_l[i * SLOTS + slot] = (unsigned short)(__float_as_uint(lo) >> 16);
            }
        }
        #pragma unroll 4
        for (int d = 0; d < T_ROWS; ++d) {
            const float dt  = fmaf((float)(d - 15), DELTA_F, av);
            const float val = __expf(-(dt * dt) * ist);
            const unsigned u = __float_as_uint(val);
            const unsigned r = u + 0x7fffu + ((u >> 16) & 1u);   // RNE to bf16
            Tt[d * SLOTS + slot] = (unsigned short)(r >> 16);
        }
    }
    if (t < 64) {   // q per 4-slot group
        const unsigned g4 = (unsigned)(t * 4);
        int qq = 0;
        #pragma unroll
        for (int bq = 0; bq < 16; ++bq)
            if (g4 >= base_s[bq] && g4 < base_s[bq + 1]) qq = bq;
        grpq[t] = (unsigned char)qq;
    }
    __syncthreads();

    // ---- stage 1: D[j=(r,ti)][i] = sum_slots Tt[d(q,r,ti)][s]*afe[i][s] ----
    floatx4 acc[7];
    #pragma unroll
    for (int ci = 0; ci < 7; ++ci) acc[ci] = floatx4{0.f, 0.f, 0.f, 0.f};

    const int nslot = (int)base_s[16];
    const int nkbf  = nslot >> 5;
    const int rem   = nslot & 31;
    const int nkb   = (nslot + 31) >> 5;
    const int rhi   = 16 + (lr < 9 ? lr : 8);   // clamped B row for nt=1 (value-masked for lr>=9)

    for (int kb = 0; kb < nkb; ++kb) {
        const bool tail = (kb == nkbf);   // only possible when rem != 0
        const int  vb   = kb * 32 + 8 * lk;
        bool h0 = true, h1 = true;
        int  vb0 = vb;
        if (tail) {
            h0 = (8 * lk) < rem;
            h1 = (8 * lk + 4) < rem;
            vb0 = h0 ? vb : 0;
        }
        const int g0 = vb0 >> 2;
        const unsigned qa = grpq[g0];
        const unsigned qb = grpq[g0 + 1];

        short8v bh0 = *(const short8v*)&afe_h[lr * SLOTS + vb0];
        short8v bl0 = *(const short8v*)&afe_l[lr * SLOTS + vb0];
        short8v bh1 = *(const short8v*)&afe_h[rhi * SLOTS + vb0];
        short8v bl1 = *(const short8v*)&afe_l[rhi * SLOTS + vb0];
        if (lr >= 9) {   // rows >=25 are zero
            bh1 = (short8v){0,0,0,0,0,0,0,0};
            bl1 = (short8v){0,0,0,0,0,0,0,0};
        }
        if (tail) {
            uintx4 u0 = __builtin_bit_cast(uintx4, bh0), u1 = __builtin_bit_cast(uintx4, bl0);
            uintx4 u2 = __builtin_bit_cast(uintx4, bh1), u3 = __builtin_bit_cast(uintx4, bl1);
            if (!h0) { u0.x=0; u0.y=0; u1.x=0; u1.y=0; u2.x=0; u2.y=0; u3.x=0; u3.y=0; }
            if (!h1) { u0.z=0; u0.w=0; u1.z=0; u1.w=0; u2.z=0; u2.w=0; u3.z=0; u3.w=0; }
            bh0 = __builtin_bit_cast(short8v, u0); bl0 = __builtin_bit_cast(short8v, u1);
            bh1 = __builtin_bit_cast(short8v, u2); bl1 = __builtin_bit_cast(short8v, u3);
        }

        #pragma unroll
        for (int ci = 0; ci < 7; ++ci) {
            const int tile = wv + 5 * ci;
            if (tile < 32) {
                const int mt = tile >> 1;   // rotation r; A row j=16*mt+lr -> ti=lr
                const int da = 15 - lr + (int)((qa + (unsigned)mt) & 15u);
                const int db = 15 - lr + (int)((qb + (unsigned)mt) & 15u);
                const uint2 alo = *(const uint2*)&Tt[da * SLOTS + vb0];
                const uint2 ahi = *(const uint2*)&Tt[db * SLOTS + vb0 + 4];
                const short8v ah = mk_frag(alo.x, alo.y, ahi.x, ahi.y);
                const short8v bh = (tile & 1) ? bh1 : bh0;
                const short8v bl = (tile & 1) ? bl1 : bl0;
                acc[ci] = __builtin_amdgcn_mfma_f32_16x16x32_bf16(ah, bh, acc[ci], 0, 0, 0);
                acc[ci] = __builtin_amdgcn_mfma_f32_16x16x32_bf16(ah, bl, acc[ci], 0, 0, 0);
            }
        }
    }
    __syncthreads();   // all reads of Tt/afe done

    // ---- write D_s [ti*16+r][27] over Tt/afe region ----
    #pragma unroll
    for (int ci = 0; ci < 7; ++ci) {
        const int tile = wv + 5 * ci;
        if (tile < 32) {
            const int mt = tile >> 1;          // r
            const int nt = tile & 1;
            const int i  = 16 * nt + lr;
            if (i < 25) {
                #pragma unroll
                for (int q = 0; q < 4; ++q) {
                    const int ti = 4 * lk + q;
                    D_s[(ti * 16 + mt) * D_ROW + i] = acc[ci][q];
                }
            }
        }
    }
    __syncthreads();

    // ---- stage 3: conv as MFMA with in-register desc. C[r][h] = sum_g desc[f][r][g]*W[f][g][h] ----
    {
        const int hcol = 16 * wv + lr;   // 0..79 (wave wv owns h-tile)
        const bool useWt = (Wt_h != nullptr);
        floatx4 acc2[4];
        #pragma unroll
        for (int f = 0; f < 4; ++f) acc2[f] = floatx4{0.f, 0.f, 0.f, 0.f};

        #pragma unroll
        for (int ks = 0; ks < 3; ++ks) {
            const int g0 = ks * 32 + 8 * lk;
            float rden[8];
            #pragma unroll
            for (int e = 0; e < 8; ++e) {
                const int g = g0 + e;
                if (g < NG) {
                    const int ti = g & 15, ri = g >> 4;
                    rden[e] = __builtin_amdgcn_rcpf(D_s[(ti * 16 + lr) * D_ROW + ri] + 1e-5f);
                } else rden[e] = 0.0f;
            }
            #pragma unroll
            for (int f = 0; f < 4; ++f) {
                short8v wfh, wfl;
                if (useWt) {
                    const size_t wo = (size_t)(f * NG + hcol) * 96 + g0;
                    wfh = *(const short8v*)&Wt_h[wo];
                    wfl = *(const short8v*)&Wt_l[wo];
                } else {
                    unsigned wh[4], wl[4];
                    #pragma unroll
                    for (int w2 = 0; w2 < 4; ++w2) {
                        const int ga = g0 + 2 * w2, gb = ga + 1;
                        float v0 = 0.f, v1 = 0.f;
                        if (ga < NG) v0 = W_conv[((size_t)(f * NG + ga)) * NG + hcol];
                        if (gb < NG) v1 = W_conv[((size_t)(f * NG + gb)) * NG + hcol];
                        const unsigned ua  = __float_as_uint(v0);
                        const unsigned ha  = ua & 0xffff0000u;
                        const float    la  = v0 - __uint_as_float(ha);
                        const unsigned ub  = __float_as_uint(v1);
                        const unsigned hb2 = ub & 0xffff0000u;
                        const float    lb  = v1 - __uint_as_float(hb2);
                        wh[w2] = (ua >> 16) | hb2;
                        wl[w2] = (__float_as_uint(la) >> 16) | (__float_as_uint(lb) & 0xffff0000u);
                    }
                    wfh = mk_frag(wh[0], wh[1], wh[2], wh[3]);
                    wfl = mk_frag(wl[0], wl[1], wl[2], wl[3]);
                }
                unsigned dh[4], dl[4];
                #pragma unroll
                for (int w2 = 0; w2 < 4; ++w2) {
                    float pv[2];
                    #pragma unroll
                    for (int p = 0; p < 2; ++p) {
                        const int e = 2 * w2 + p;
                        const int g = g0 + e;
                        float dv = 0.0f;
                        if (g < NG) {
                            const int ti = g & 15, ri = g >> 4;
                            dv = D_s[(ti * 16 + lr) * D_ROW + (f + 1) * 5 + ri] * rden[e];
                        }
                        pv[p] = dv;
                    }
                    const unsigned ua = __float_as_uint(pv[0]);
                    const unsigned ha = ua & 0xffff0000u;
                    const float    la = pv[0] - __uint_as_float(ha);
                    const unsigned ub = __float_as_uint(pv[1]);
                    const unsigned hb2 = ub & 0xffff0000u;
                    const float    lb = pv[1] - __uint_as_float(hb2);
                    dh[w2] = (ua >> 16) | hb2;
                    dl[w2] = (__float_as_uint(la) >> 16) | (__float_as_uint(lb) & 0xffff0000u);
                }
                const short8v dhv = mk_frag(dh[0], dh[1], dh[2], dh[3]);
                const short8v dlv = mk_frag(dl[0], dl[1], dl[2], dl[3]);
                acc2[f] = __builtin_amdgcn_mfma_f32_16x16x32_bf16(dhv, wfh, acc2[f], 0, 0, 0);
                acc2[f] = __builtin_amdgcn_mfma_f32_16x16x32_bf16(dhv, wfl, acc2[f], 0, 0, 0);
                acc2[f] = __builtin_amdgcn_mfma_f32_16x16x32_bf16(dlv, wfh, acc2[f], 0, 0, 0);
            }
        }
        __syncthreads();   // D_s reads done; x_s region safe
        #pragma unroll
        for (int f = 0; f < 4; ++f) {
            float mx = fmaxf(fmaxf(acc2[f][0], acc2[f][1]), fmaxf(acc2[f][2], acc2[f][3]));
            mx = fmaxf(mx, __shfl_xor(mx, 16));
            mx = fmaxf(mx, __shfl_xor(mx, 32));
            if (lk == 0) x_s[f * NG + hcol] = mx;
        }
    }
    __syncthreads();

    // ---- bias + BN + relu ----
    {
        const float cm = x_s[t] + b_conv[t];
        const float xv = (cm - bn_mean[t]) * rsqrtf(bn_var[t] + 1e-3f) * bn_gamma[t] + bn_beta[t];
        x_s[t] = fmaxf(xv, 0.0f);
    }
    __syncthreads();

    // ---- d1: 320->80 relu (4 partials x 80 h) ----
    {
        const int part = t / NG;
        const int h    = t - part * NG;
        const int ib   = part * NG;
        float a = 0.0f;
        #pragma unroll 8
        for (int i2 = 0; i2 < NG; ++i2)
            a = fmaf(x_s[ib + i2], d1_w[(size_t)(ib + i2) * NG + h], a);
        y1p[part * NG + h] = a;
    }
    __syncthreads();
    if (t < NG) {
        const float a = d1_b[t] + y1p[t] + y1p[NG + t] + y1p[2 * NG + t] + y1p[3 * NG + t];
        y1_s[t] = fmaxf(a, 0.0f);
    }
    __syncthreads();

    // ---- d2: 80->4 relu ----
    if (t < NF) {
        float a = d2_b[t];
        #pragma unroll 8
        for (int i = 0; i < NG; ++i)
            a = fmaf(y1_s[i], d2_w[(size_t)i * NF + t], a);
        a = fmaxf(a, 0.0f);
        if (MODE < 2) x_out[(size_t)bs * NF + t] = a;
        else          y2_s[t] = a;
    }

    if (MODE == 2) {
        __syncthreads();
        if (t < 16) {
            float a = d3_b[t];
            #pragma unroll
            for (int ff = 0; ff < NF; ++ff)
                a = fmaf(y2_s[ff], d3_w[ff * 16 + t], a);
            y3_s[t] = fmaxf(a, 0.0f);
        }
        __syncthreads();
        if (t == 0) {
            float a = out_b[0];
            #pragma unroll
            for (int k = 0; k < 16; ++k)
                a = fmaf(y3_s[k], out_w[k], a);
            x_out[bs] = a;
        }
    }
}

extern "C" void kernel_launch(void* const* d_in, const int* in_sizes, int n_in,
                              void* d_out, int out_size, void* d_ws, size_t ws_size,
                              hipStream_t stream) {
    const float* input_feat  = (const float*)d_in[0];
    const float* rho         = (const float*)d_in[1];
    const float* theta       = (const float*)d_in[2];
    const float* mask        = (const float*)d_in[3];
    const float* mu_rho      = (const float*)d_in[4];
    const float* sigma_rho   = (const float*)d_in[6];
    const float* sigma_theta = (const float*)d_in[7];
    const float* W_conv      = (const float*)d_in[8];
    const float* b_conv      = (const float*)d_in[9];
    const float* bn_gamma    = (const float*)d_in[10];
    const float* bn_beta     = (const float*)d_in[11];
    const float* bn_mean     = (const float*)d_in[12];
    const float* bn_var      = (const float*)d_in[13];
    const float* d1_w        = (const float*)d_in[14];
    const float* d1_b        = (const float*)d_in[15];
    const float* d2_w        = (const float*)d_in[16];
    const float* d2_b        = (const float*)d_in[17];
    const float* d3_w        = (const float*)d_in[18];
    const float* d3_b        = (const float*)d_in[19];
    const float* out_w       = (const float*)d_in[20];
    const float* out_b       = (const float*)d_in[21];
    const int*   indices     = (const int*)d_in[22];

    float* x1  = (float*)d_ws;                 // [4096] f32
    float* x2  = x1 + (size_t)NB * NS * NF;    // [4096] f32
    float* out = (float*)d_out;

    const size_t WT_OFF   = 32768;
    const size_t WT_BYTES = (size_t)2 * WT_ELEMS * 2;   // 122880
    unsigned short* Wh = nullptr;
    unsigned short* Wl = nullptr;
    if (ws_size >= WT_OFF + WT_BYTES) {
        Wh = (unsigned short*)((char*)d_ws + WT_OFF);
        Wl = Wh + WT_ELEMS;
        prep_w_kernel<<<(WT_ELEMS + 255) / 256, 256, 0, stream>>>(W_conv, Wh, Wl);
    }

    dim3 grid(NB * NS), block(NFG);

    masif_block_kernel<0><<<grid, block, 0, stream>>>(
        input_feat, rho, theta, mask, mu_rho, sigma_rho, sigma_theta,
        W_conv, Wh, Wl, b_conv, bn_gamma, bn_beta, bn_mean, bn_var,
        d1_w, d1_b, d2_w, d2_b, d3_w, d3_b, out_w, out_b, indices, nullptr, x1);

    masif_block_kernel<1><<<grid, block, 0, stream>>>(
        input_feat, rho, theta, mask, mu_rho, sigma_rho, sigma_theta,
        W_conv, Wh, Wl, b_conv, bn_gamma, bn_beta, bn_mean, bn_var,
        d1_w, d1_b, d2_w, d2_b, d3_w, d3_b, out_w, out_b, indices, x1, x2);

    masif_block_kernel<2><<<grid, block, 0, stream>>>(
        input_feat, rho, theta, mask, mu_rho, sigma_rho, sigma_theta,
        W_conv, Wh, Wl, b_conv, bn_gamma, bn_beta, bn_mean, bn_var,
        d1_w, d1_b, d2_w, d2_b, d3_w, d3_b, out_w, out_b, indices, x2, out);
}

// Round 8
// 92.012 us; speedup vs baseline: 14.5455x; 1.3122x over previous
//
#include <hip/hip_runtime.h>
#include <math.h>

#define NB 4
#define NS 256
#define NV 200
#define NF 4
#define NG 80
#define NFG 320
#define NROT 16
#define DELTA_F 0.39269908169872414f      // 2pi/16
#define INV_DELTA_F 2.5464790894703254f   // 16/2pi

#define SLOTS 248        // afe columns (row 496B = 31*16 -> b128-aligned, 2-way banks)
#define TT_STRIDE 252    // Tt columns  (row 504B: 8B-aligned b64, 126dw -> 2-way banks)
#define T_ROWS 31
#define D_ROW 27         // f32, odd stride -> conflict-free by-row reads

// single hand-placed smem block:
//  pre-stage1 : Tt u16[31][252] @0      (15624B)
//               afe_h u16[25][248] @15632 (12400B)   -> 28032
//  post-stage1: D_s f32[256][27] @0     (27648B)
//               x_s[320]|y1p[320]|y1_s[80]|y2[4]|y3[16] f32 @27648 (2960B) -> 30608
//  aux        : wcnt16 u16[64] @30608 | base_s u32[17] @30736 | grpq u8[64] @30804
#define AFE_OFF   15632
#define X_OFF     27648
#define AUX_WCNT  30608
#define AUX_BASE  30736
#define AUX_GRPQ  30804
#define SMEM_BYTES 30880
#define ZERO_BYTES 28032

#define WT_ELEMS (4 * 3 * 5 * 64 * 8)   // 30720 (f, ks, wv-tile, lane, 8 elems)

typedef __attribute__((ext_vector_type(8))) short short8v;   // 8 bf16
typedef __attribute__((ext_vector_type(4))) float floatx4;   // MFMA acc
typedef __attribute__((ext_vector_type(4))) unsigned int uintx4;

__device__ __forceinline__ short8v mk_frag(unsigned a, unsigned b, unsigned c, unsigned d) {
    uintx4 v = {a, b, c, d};
    return __builtin_bit_cast(short8v, v);
}
__device__ __forceinline__ unsigned short rne_bf16(float v) {
    const unsigned u = __float_as_uint(v);
    return (unsigned short)((u + 0x7fffu + ((u >> 16) & 1u)) >> 16);
}

// Pre-pack W fragments in exact MFMA lane order:
// Wh/Wl[(((f*3+ks)*5+wvt)*64+lane)*8+e] = bf16 of W[f][g][h], g=ks*32+(lane>>4)*8+e, h=16*wvt+(lane&15)
__global__ __launch_bounds__(256) void prep_w_kernel(
    const float* __restrict__ W, unsigned short* __restrict__ Wh, unsigned short* __restrict__ Wl)
{
    const int G = blockIdx.x * 256 + threadIdx.x;
    if (G >= WT_ELEMS) return;
    const int e    = G & 7;
    const int lane = (G >> 3) & 63;
    int rest = G >> 9;
    const int wvt = rest % 5;  rest /= 5;
    const int ks  = rest % 3;
    const int f   = rest / 3;
    const int g   = ks * 32 + (lane >> 4) * 8 + e;
    const int h   = 16 * wvt + (lane & 15);
    float v = 0.0f;
    if (g < NG) v = W[((size_t)(f * NG + g)) * NG + h];
    const unsigned u  = __float_as_uint(v);
    const unsigned hb = u & 0xffff0000u;
    const float    lo = v - __uint_as_float(hb);
    Wh[G] = (unsigned short)(u >> 16);
    Wl[G] = (unsigned short)(__float_as_uint(lo) >> 16);
}

template<int MODE>
__global__ __launch_bounds__(NFG, 6) void masif_block_kernel(
    const float* __restrict__ input_feat,
    const float* __restrict__ rho,
    const float* __restrict__ theta,
    const float* __restrict__ mask,
    const float* __restrict__ mu_rho,
    const float* __restrict__ sigma_rho,
    const float* __restrict__ sigma_theta,
    const float* __restrict__ W_conv,
    const unsigned short* __restrict__ Wt_h,
    const unsigned short* __restrict__ Wt_l,
    const float* __restrict__ b_conv,
    const float* __restrict__ bn_gamma,
    const float* __restrict__ bn_beta,
    const float* __restrict__ bn_mean,
    const float* __restrict__ bn_var,
    const float* __restrict__ d1_w,
    const float* __restrict__ d1_b,
    const float* __restrict__ d2_w,
    const float* __restrict__ d2_b,
    const float* __restrict__ d3_w,
    const float* __restrict__ d3_b,
    const float* __restrict__ out_w,
    const float* __restrict__ out_b,
    const int*   __restrict__ indices,
    const float* __restrict__ x_in,
    float*       __restrict__ x_out)
{
    const int bs = blockIdx.x;
    const int t  = threadIdx.x;
    const int lane = t & 63;
    const int lr   = lane & 15;
    const int lk   = lane >> 4;
    const int wv   = t >> 6;          // wave 0..4

    __shared__ __align__(16) char smem[SMEM_BYTES];

    unsigned short* Tt     = (unsigned short*)smem;                  // [31][252]
    unsigned short* afe_h  = (unsigned short*)(smem + AFE_OFF);      // [25][248]
    float*          D_s    = (float*)smem;                           // [256][27], row = ti*16 + r
    float*          x_s    = (float*)(smem + X_OFF);                 // [320]
    float*          y1p    = x_s + NFG;                              // [320]
    float*          y1_s   = y1p + NFG;                              // [80]
    float*          y2_s   = y1_s + NG;                              // [4]
    float*          y3_s   = y2_s + NF;                              // [16]
    unsigned short* wcnt16 = (unsigned short*)(smem + AUX_WCNT);     // [4*16]
    unsigned int*   base_s = (unsigned int*)(smem + AUX_BASE);       // [17]
    unsigned char*  grpq   = (unsigned char*)(smem + AUX_GRPQ);      // [64]

    const int base = bs * NV;
    const int b    = bs / NS;

    const float sr  = sigma_rho[0];
    const float st  = sigma_theta[0];
    const float isr = 1.0f / (sr * sr + 1e-5f);
    const float ist = 1.0f / (st * st + 1e-5f);

    // ---- step0: zero Tt+afe; load per-vertex; q; wave-ballot rank ----
    for (int off = t * 16; off < ZERO_BYTES; off += NFG * 16)
        *(uintx4*)(smem + off) = (uintx4){0u, 0u, 0u, 0u};

    const bool valid = (t < NV);
    float rv = 0.0f, mv = 0.0f, thv = 0.0f, av = 0.0f;
    float4 fv = {0.f, 0.f, 0.f, 0.f};
    int myq = 0, rank = 0;
    if (valid) {
        rv  = rho[base + t];
        mv  = mask[base + t];
        thv = theta[base + t];
        if (MODE == 0) {
            fv = *reinterpret_cast<const float4*>(&input_feat[(size_t)(base + t) * NF]);
        } else {
            const int idx = indices[base + t];
            fv = *reinterpret_cast<const float4*>(&x_in[(size_t)(b * NS + idx) * NF]);
        }
        const float qf = floorf(thv * INV_DELTA_F);
        av  = fmaf(-qf, DELTA_F, thv);
        myq = ((int)qf) & 15;
    }
    {
        unsigned long long mymask = 0ull;
        #pragma unroll
        for (int bq = 0; bq < 16; ++bq) {
            const unsigned long long m = __ballot(valid && (myq == bq));
            if (wv < 4 && lane == bq) wcnt16[wv * 16 + bq] = (unsigned short)__popcll(m);
            if (valid && myq == bq) mymask = m;
        }
        rank = (int)__popcll(mymask & ((1ull << lane) - 1ull));
    }
    __syncthreads();

    // ---- padded prefix ----
    if (t == 0) {
        unsigned s = 0;
        #pragma unroll
        for (int bq = 0; bq < 16; ++bq) {
            base_s[bq] = s;
            unsigned c = (unsigned)wcnt16[bq] + wcnt16[16 + bq] + wcnt16[32 + bq] + wcnt16[48 + bq];
            s += (c + 3u) & ~3u;
        }
        base_s[16] = s;   // nslot (multiple of 4, <= 248)
    }
    __syncthreads();

    // ---- scatter: afe rows (single RNE bf16) + transposed T via exp-recurrence ----
    if (valid) {
        int rk = rank;
        #pragma unroll
        for (int w = 0; w < 3; ++w)
            if (wv > w) rk += wcnt16[w * 16 + myq];
        const int slot = (int)base_s[myq] + rk;

        const float w5[5] = {mv, mv * fv.x, mv * fv.y, mv * fv.z, mv * fv.w};
        #pragma unroll
        for (int ri = 0; ri < 5; ++ri) {
            const float dr = rv - mu_rho[ri * 16];
            const float R  = __expf(-(dr * dr) * isr);
            #pragma unroll
            for (int fp = 0; fp < 5; ++fp)
                afe_h[(fp * 5 + ri) * SLOTS + slot] = rne_bf16(w5[fp] * R);
        }
        // T[v][d] = exp(-(a+(d-15)Delta)^2 * ist) via multiplicative recurrence
        const float gb1 = __expf(-ist * DELTA_F * DELTA_F);
        const float gb2 = gb1 * gb1;
        const float E2  = __expf(-2.0f * av * DELTA_F * ist);
        const float E2i = __builtin_amdgcn_rcpf(E2);
        const float f0  = __expf(-(av * av) * ist);
        Tt[15 * TT_STRIDE + slot] = rne_bf16(f0);
        float f = f0, h = E2 * gb1;
        #pragma unroll 5
        for (int k = 0; k < 15; ++k) {
            f *= h; h *= gb2;
            Tt[(16 + k) * TT_STRIDE + slot] = rne_bf16(f);
        }
        f = f0; h = E2i * gb1;
        #pragma unroll 5
        for (int k = 0; k < 15; ++k) {
            f *= h; h *= gb2;
            Tt[(14 - k) * TT_STRIDE + slot] = rne_bf16(f);
        }
    }
    if (t < 64) {   // q per 4-slot group
        const unsigned g4 = (unsigned)(t * 4);
        int qq = 0;
        #pragma unroll
        for (int bq = 0; bq < 16; ++bq)
            if (g4 >= base_s[bq] && g4 < base_s[bq + 1]) qq = bq;
        grpq[t] = (unsigned char)qq;
    }
    __syncthreads();

    // ---- stage 1: D[j=(r,ti)][i] = sum_slots Tt[d(q,r,ti)][s]*afe[i][s] ----
    floatx4 acc[7];
    #pragma unroll
    for (int ci = 0; ci < 7; ++ci) acc[ci] = floatx4{0.f, 0.f, 0.f, 0.f};

    const int nslot = (int)base_s[16];
    const int nkbf  = nslot >> 5;
    const int rem   = nslot & 31;
    const int nkb   = (nslot + 31) >> 5;
    const int rhi   = 16 + (lr < 9 ? lr : 8);   // clamped B row for nt=1 (value-masked lr>=9)

    for (int kb = 0; kb < nkb; ++kb) {
        const bool tail = (kb == nkbf);
        const int  vb   = kb * 32 + 8 * lk;
        bool h0 = true, h1 = true;
        int  vb0 = vb;
        if (tail) {
            h0 = (8 * lk) < rem;
            h1 = (8 * lk + 4) < rem;
            vb0 = h0 ? vb : 0;
        }
        const int g0 = vb0 >> 2;
        const unsigned qa = grpq[g0];
        const unsigned qb = grpq[g0 + 1];

        short8v bh0 = *(const short8v*)&afe_h[lr * SLOTS + vb0];
        short8v bh1 = *(const short8v*)&afe_h[rhi * SLOTS + vb0];
        if (lr >= 9) bh1 = (short8v){0,0,0,0,0,0,0,0};
        if (tail) {
            uintx4 u0 = __builtin_bit_cast(uintx4, bh0);
            uintx4 u2 = __builtin_bit_cast(uintx4, bh1);
            if (!h0) { u0.x=0; u0.y=0; u2.x=0; u2.y=0; }
            if (!h1) { u0.z=0; u0.w=0; u2.z=0; u2.w=0; }
            bh0 = __builtin_bit_cast(short8v, u0);
            bh1 = __builtin_bit_cast(short8v, u2);
        }

        #pragma unroll
        for (int ci = 0; ci < 7; ++ci) {
            const int tile = wv + 5 * ci;
            if (tile < 32) {
                const int mt = tile >> 1;   // rotation r; A row j=16*mt+lr -> ti=lr
                const int da = 15 - lr + (int)((qa + (unsigned)mt) & 15u);
                const int db = 15 - lr + (int)((qb + (unsigned)mt) & 15u);
                const uint2 alo = *(const uint2*)&Tt[da * TT_STRIDE + vb0];
                const uint2 ahi = *(const uint2*)&Tt[db * TT_STRIDE + vb0 + 4];
                const short8v ah = mk_frag(alo.x, alo.y, ahi.x, ahi.y);
                acc[ci] = __builtin_amdgcn_mfma_f32_16x16x32_bf16(
                    ah, (tile & 1) ? bh1 : bh0, acc[ci], 0, 0, 0);
            }
        }
    }
    __syncthreads();   // all reads of Tt/afe done

    // ---- write D_s [ti*16+r][27] over Tt/afe region ----
    #pragma unroll
    for (int ci = 0; ci < 7; ++ci) {
        const int tile = wv + 5 * ci;
        if (tile < 32) {
            const int mt = tile >> 1;          // r
            const int nt = tile & 1;
            const int i  = 16 * nt + lr;
            if (i < 25) {
                #pragma unroll
                for (int q = 0; q < 4; ++q) {
                    const int ti = 4 * lk + q;
                    D_s[(ti * 16 + mt) * D_ROW + i] = acc[ci][q];
                }
            }
        }
    }
    __syncthreads();

    // ---- stage 3: conv as MFMA with in-register desc ----
    {
        const int hcol = 16 * wv + lr;
        const bool useWt = (Wt_h != nullptr);
        floatx4 acc2[4];
        #pragma unroll
        for (int f = 0; f < 4; ++f) acc2[f] = floatx4{0.f, 0.f, 0.f, 0.f};

        #pragma unroll
        for (int ks = 0; ks < 3; ++ks) {
            const int g0 = ks * 32 + 8 * lk;
            float rden[8];
            #pragma unroll
            for (int e = 0; e < 8; ++e) {
                const int g = g0 + e;
                if (g < NG) {
                    const int ti = g & 15, ri = g >> 4;
                    rden[e] = __builtin_amdgcn_rcpf(D_s[(ti * 16 + lr) * D_ROW + ri] + 1e-5f);
                } else rden[e] = 0.0f;
            }
            #pragma unroll
            for (int f = 0; f < 4; ++f) {
                short8v wfh, wfl;
                if (useWt) {
                    const size_t wo = ((size_t)(((f * 3 + ks) * 5 + wv) * 64 + lane)) * 8;
                    wfh = *(const short8v*)&Wt_h[wo];
                    wfl = *(const short8v*)&Wt_l[wo];
                } else {
                    unsigned wh[4], wl[4];
                    #pragma unroll
                    for (int w2 = 0; w2 < 4; ++w2) {
                        const int ga = g0 + 2 * w2, gb = ga + 1;
                        float v0 = 0.f, v1 = 0.f;
                        if (ga < NG) v0 = W_conv[((size_t)(f * NG + ga)) * NG + hcol];
                        if (gb < NG) v1 = W_conv[((size_t)(f * NG + gb)) * NG + hcol];
                        const unsigned ua  = __float_as_uint(v0);
                        const unsigned ha  = ua & 0xffff0000u;
                        const float    la  = v0 - __uint_as_float(ha);
                        const unsigned ub  = __float_as_uint(v1);
                        const unsigned hb2 = ub & 0xffff0000u;
                        const float    lb  = v1 - __uint_as_float(hb2);
                        wh[w2] = (ua >> 16) | hb2;
                        wl[w2] = (__float_as_uint(la) >> 16) | (__float_as_uint(lb) & 0xffff0000u);
                    }
                    wfh = mk_frag(wh[0], wh[1], wh[2], wh[3]);
                    wfl = mk_frag(wl[0], wl[1], wl[2], wl[3]);
                }
                unsigned dh[4], dl[4];
                #pragma unroll
                for (int w2 = 0; w2 < 4; ++w2) {
                    float pv[2];
                    #pragma unroll
                    for (int p = 0; p < 2; ++p) {
                        const int e = 2 * w2 + p;
                        const int g = g0 + e;
                        float dv = 0.0f;
                        if (g < NG) {
                            const int ti = g & 15, ri = g >> 4;
                            dv = D_s[(ti * 16 + lr) * D_ROW + (f + 1) * 5 + ri] * rden[e];
                        }
                        pv[p] = dv;
                    }
                    const unsigned ua = __float_as_uint(pv[0]);
                    const unsigned ha = ua & 0xffff0000u;
                    const float    la = pv[0] - __uint_as_float(ha);
                    const unsigned ub = __float_as_uint(pv[1]);
                    const unsigned hb2 = ub & 0xffff0000u;
                    const float    lb = pv[1] - __uint_as_float(hb2);
                    dh[w2] = (ua >> 16) | hb2;
                    dl[w2] = (__float_as_uint(la) >> 16) | (__float_as_uint(lb) & 0xffff0000u);
                }
                const short8v dhv = mk_frag(dh[0], dh[1], dh[2], dh[3]);
                const short8v dlv = mk_frag(dl[0], dl[1], dl[2], dl[3]);
                acc2[f] = __builtin_amdgcn_mfma_f32_16x16x32_bf16(dhv, wfh, acc2[f], 0, 0, 0);
                acc2[f] = __builtin_amdgcn_mfma_f32_16x16x32_bf16(dhv, wfl, acc2[f], 0, 0, 0);
                acc2[f] = __builtin_amdgcn_mfma_f32_16x16x32_bf16(dlv, wfh, acc2[f], 0, 0, 0);
            }
        }
        __syncthreads();   // D_s reads done; x_s region safe
        #pragma unroll
        for (int f = 0; f < 4; ++f) {
            float mx = fmaxf(fmaxf(acc2[f][0], acc2[f][1]), fmaxf(acc2[f][2], acc2[f][3]));
            mx = fmaxf(mx, __shfl_xor(mx, 16));
            mx = fmaxf(mx, __shfl_xor(mx, 32));
            if (lk == 0) x_s[f * NG + hcol] = mx;
        }
    }
    __syncthreads();

    // ---- bias + BN + relu ----
    {
        const float cm = x_s[t] + b_conv[t];
        const float xv = (cm - bn_mean[t]) * rsqrtf(bn_var[t] + 1e-3f) * bn_gamma[t] + bn_beta[t];
        x_s[t] = fmaxf(xv, 0.0f);
    }
    __syncthreads();

    // ---- d1: 320->80 relu (4 partials x 80 h) ----
    {
        const int part = t / NG;
        const int h    = t - part * NG;
        const int ib   = part * NG;
        float a = 0.0f;
        #pragma unroll 8
        for (int i2 = 0; i2 < NG; ++i2)
            a = fmaf(x_s[ib + i2], d1_w[(size_t)(ib + i2) * NG + h], a);
        y1p[part * NG + h] = a;
    }
    __syncthreads();
    if (t < NG) {
        const float a = d1_b[t] + y1p[t] + y1p[NG + t] + y1p[2 * NG + t] + y1p[3 * NG + t];
        y1_s[t] = fmaxf(a, 0.0f);
    }
    __syncthreads();

    // ---- d2: 80->4 relu ----
    if (t < NF) {
        float a = d2_b[t];
        #pragma unroll 8
        for (int i = 0; i < NG; ++i)
            a = fmaf(y1_s[i], d2_w[(size_t)i * NF + t], a);
        a = fmaxf(a, 0.0f);
        if (MODE < 2) x_out[(size_t)bs * NF + t] = a;
        else          y2_s[t] = a;
    }

    if (MODE == 2) {
        __syncthreads();
        if (t < 16) {
            float a = d3_b[t];
            #pragma unroll
            for (int ff = 0; ff < NF; ++ff)
                a = fmaf(y2_s[ff], d3_w[ff * 16 + t], a);
            y3_s[t] = fmaxf(a, 0.0f);
        }
        __syncthreads();
        if (t == 0) {
            float a = out_b[0];
            #pragma unroll
            for (int k = 0; k < 16; ++k)
                a = fmaf(y3_s[k], out_w[k], a);
            x_out[bs] = a;
        }
    }
}

extern "C" void kernel_launch(void* const* d_in, const int* in_sizes, int n_in,
                              void* d_out, int out_size, void* d_ws, size_t ws_size,
                              hipStream_t stream) {
    const float* input_feat  = (const float*)d_in[0];
    const float* rho         = (const float*)d_in[1];
    const float* theta       = (const float*)d_in[2];
    const float* mask        = (const float*)d_in[3];
    const float* mu_rho      = (const float*)d_in[4];
    const float* sigma_rho   = (const float*)d_in[6];
    const float* sigma_theta = (const float*)d_in[7];
    const float* W_conv      = (const float*)d_in[8];
    const float* b_conv      = (const float*)d_in[9];
    const float* bn_gamma    = (const float*)d_in[10];
    const float* bn_beta     = (const float*)d_in[11];
    const float* bn_mean     = (const float*)d_in[12];
    const float* bn_var      = (const float*)d_in[13];
    const float* d1_w        = (const float*)d_in[14];
    const float* d1_b        = (const float*)d_in[15];
    const float* d2_w        = (const float*)d_in[16];
    const float* d2_b        = (const float*)d_in[17];
    const float* d3_w        = (const float*)d_in[18];
    const float* d3_b        = (const float*)d_in[19];
    const float* out_w       = (const float*)d_in[20];
    const float* out_b       = (const float*)d_in[21];
    const int*   indices     = (const int*)d_in[22];

    float* x1  = (float*)d_ws;                 // [4096] f32
    float* x2  = x1 + (size_t)NB * NS * NF;    // [4096] f32
    float* out = (float*)d_out;

    const size_t WT_OFF   = 32768;
    const size_t WT_BYTES = (size_t)2 * WT_ELEMS * 2;   // 122880
    unsigned short* Wh = nullptr;
    unsigned short* Wl = nullptr;
    if (ws_size >= WT_OFF + WT_BYTES) {
        Wh = (unsigned short*)((char*)d_ws + WT_OFF);
        Wl = Wh + WT_ELEMS;
        prep_w_kernel<<<(WT_ELEMS + 255) / 256, 256, 0, stream>>>(W_conv, Wh, Wl);
    }

    dim3 grid(NB * NS), block(NFG);

    masif_block_kernel<0><<<grid, block, 0, stream>>>(
        input_feat, rho, theta, mask, mu_rho, sigma_rho, sigma_theta,
        W_conv, Wh, Wl, b_conv, bn_gamma, bn_beta, bn_mean, bn_var,
        d1_w, d1_b, d2_w, d2_b, d3_w, d3_b, out_w, out_b, indices, nullptr, x1);

    masif_block_kernel<1><<<grid, block, 0, stream>>>(
        input_feat, rho, theta, mask, mu_rho, sigma_rho, sigma_theta,
        W_conv, Wh, Wl, b_conv, bn_gamma, bn_beta, bn_mean, bn_var,
        d1_w, d1_b, d2_w, d2_b, d3_w, d3_b, out_w, out_b, indices, x1, x2);

    masif_block_kernel<2><<<grid, block, 0, stream>>>(
        input_feat, rho, theta, mask, mu_rho, sigma_rho, sigma_theta,
        W_conv, Wh, Wl, b_conv, bn_gamma, bn_beta, bn_mean, bn_var,
        d1_w, d1_b, d2_w, d2_b, d3_w, d3_b, out_w, out_b, indices, x2, out);
}